// Round 8
// baseline (15900.589 us; speedup 1.0000x reference)
//
#include <hip/hip_runtime.h>
#include <hip/hip_cooperative_groups.h>
#include <cstdint>
#include <cstddef>

namespace cg = cooperative_groups;

#define N_NODES 50000
#define N_EDGES 800000
#define F_IN_D 100
#define HDIM 128
#define CDIM 10
#define NCH ((N_NODES + 255) / 256)   // 196 scan chunks

struct MegaArgs {
  const float* x; const int* ei; const float* ew;
  const float* W1; const float* b1;
  const float* W2; const float* b2;
  const float* W3; const float* b3;
  float* out;
  float* A; float* B; float* C; float* D;
  int* row32; int* col32; float* deg; float* dis; int* cnt;
  int* ptrA; int* pos; int* srcs; float* wsrt; int* part;
};

// ---- dense GEMM tile: out[n0:n0+64, c0:c0+64] = X @ B (+bias) ----
// BMODE 0: B[k,c]=W[k*128+c], 128 cols (tile = 2 per node-row). ostride 128.
// BMODE 1: B[k,c]=W3[(c/10)*K*10 + k*10 + c%10] (c<60), 64 cols. ostride 64.
template <int K_DIM, int BMODE, bool ADD_BIAS>
__device__ __forceinline__ void gemm_tile(const float* __restrict__ X, const float* __restrict__ W,
                                          const float* __restrict__ bias, float* __restrict__ outp,
                                          int tile, float (&xt)[32][68], float (&bt)[32][64]) {
  const int ostride = (BMODE == 0) ? 128 : 64;
  const int tid = threadIdx.x;
  const int tx = tid & 15;
  const int ty = tid >> 4;
  int n0, c0;
  if (BMODE == 0) { n0 = (tile >> 1) * 64; c0 = (tile & 1) * 64; }
  else            { n0 = tile * 64;        c0 = 0; }
  float acc[4][4];
#pragma unroll
  for (int i = 0; i < 4; ++i)
#pragma unroll
    for (int j = 0; j < 4; ++j) acc[i][j] = 0.f;

  for (int k0 = 0; k0 < K_DIM; k0 += 32) {
#pragma unroll
    for (int i = 0; i < 8; ++i) {
      int idx = tid + i * 256;
      int nl = idx >> 5, kl = idx & 31;
      int nn = n0 + nl, kg = k0 + kl;
      float v = 0.f;
      if (nn < N_NODES && kg < K_DIM) v = X[(size_t)nn * K_DIM + kg];
      xt[kl][nl] = v;
    }
#pragma unroll
    for (int i = 0; i < 8; ++i) {
      int idx = tid + i * 256;
      int kl = idx >> 6, cl = idx & 63;
      int kg = k0 + kl;
      float v = 0.f;
      if (BMODE == 0) {
        if (kg < K_DIM) v = W[(size_t)kg * 128 + c0 + cl];
      } else {
        if (kg < K_DIM && cl < 6 * CDIM)
          v = W[(size_t)(cl / CDIM) * (K_DIM * CDIM) + (size_t)kg * CDIM + (cl % CDIM)];
      }
      bt[kl][cl] = v;
    }
    __syncthreads();
#pragma unroll
    for (int kk = 0; kk < 32; ++kk) {
      float4 xv = *(const float4*)&xt[kk][tx * 4];
      float4 bv = *(const float4*)&bt[kk][ty * 4];
      acc[0][0] += xv.x * bv.x; acc[0][1] += xv.x * bv.y; acc[0][2] += xv.x * bv.z; acc[0][3] += xv.x * bv.w;
      acc[1][0] += xv.y * bv.x; acc[1][1] += xv.y * bv.y; acc[1][2] += xv.y * bv.z; acc[1][3] += xv.y * bv.w;
      acc[2][0] += xv.z * bv.x; acc[2][1] += xv.z * bv.y; acc[2][2] += xv.z * bv.z; acc[2][3] += xv.z * bv.w;
      acc[3][0] += xv.w * bv.x; acc[3][1] += xv.w * bv.y; acc[3][2] += xv.w * bv.z; acc[3][3] += xv.w * bv.w;
    }
    __syncthreads();
  }
#pragma unroll
  for (int i = 0; i < 4; ++i) {
    int nn = n0 + tx * 4 + i;
    if (nn >= N_NODES) continue;
#pragma unroll
    for (int j = 0; j < 4; ++j) {
      int c = c0 + ty * 4 + j;
      float r = acc[i][j];
      if (ADD_BIAS) {
        if (BMODE == 0) r += bias[c];
        else if (c < CDIM) r += bias[c];
      }
      outp[(size_t)nn * ostride + c] = r;
    }
  }
}

// ---- hop d=128 fp32: Q[n][:] = maybeELU( Y[n][:] + sum_j w_j * P[src_j][:] ) ----
// wave per node; 2 halves × 4-edge unroll; combine via shfl_xor(32)
template <bool ELU>
__device__ __forceinline__ void hop128_phase(const float* __restrict__ P, const float* __restrict__ Y,
                                             const int* __restrict__ ptr, const int* __restrict__ srcs,
                                             const float* __restrict__ w, float* __restrict__ Q) {
  const int lane = threadIdx.x & 63;
  const int wid = threadIdx.x >> 6;
  const int half = lane >> 5;
  const int f4 = lane & 31;
  const float4* s4 = (const float4*)P;
  for (int node = blockIdx.x * 4 + wid; node < N_NODES; node += gridDim.x * 4) {
    const int b = ptr[node], e = ptr[node + 1];
    const int len = e - b;
    const int c0 = (len + 1) >> 1;
    const int js = half ? (b + c0) : b;
    const int je = half ? e : (b + c0);
    float4 acc;
    if (half == 0) acc = ((const float4*)Y)[(size_t)node * 32 + f4];
    else           acc = make_float4(0.f, 0.f, 0.f, 0.f);
    int j = js;
    for (; j + 3 < je; j += 4) {
      int s0 = srcs[j], s1 = srcs[j + 1], s2 = srcs[j + 2], s3 = srcs[j + 3];
      float w0 = w[j], w1 = w[j + 1], w2 = w[j + 2], w3 = w[j + 3];
      float4 v0 = s4[(size_t)s0 * 32 + f4];
      float4 v1 = s4[(size_t)s1 * 32 + f4];
      float4 v2 = s4[(size_t)s2 * 32 + f4];
      float4 v3 = s4[(size_t)s3 * 32 + f4];
      acc.x += w0 * v0.x + w1 * v1.x + w2 * v2.x + w3 * v3.x;
      acc.y += w0 * v0.y + w1 * v1.y + w2 * v2.y + w3 * v3.y;
      acc.z += w0 * v0.z + w1 * v1.z + w2 * v2.z + w3 * v3.z;
      acc.w += w0 * v0.w + w1 * v1.w + w2 * v2.w + w3 * v3.w;
    }
    for (; j < je; ++j) {
      float w0 = w[j];
      float4 v0 = s4[(size_t)srcs[j] * 32 + f4];
      acc.x += w0 * v0.x; acc.y += w0 * v0.y; acc.z += w0 * v0.z; acc.w += w0 * v0.w;
    }
    acc.x += __shfl_xor(acc.x, 32);
    acc.y += __shfl_xor(acc.y, 32);
    acc.z += __shfl_xor(acc.z, 32);
    acc.w += __shfl_xor(acc.w, 32);
    if (half == 0) {
      if (ELU) {
        acc.x = acc.x > 0.f ? acc.x : expm1f(acc.x);
        acc.y = acc.y > 0.f ? acc.y : expm1f(acc.y);
        acc.z = acc.z > 0.f ? acc.z : expm1f(acc.z);
        acc.w = acc.w > 0.f ? acc.w : expm1f(acc.w);
      }
      ((float4*)Q)[(size_t)node * 32 + f4] = acc;
    }
  }
}

// ---- hop d=10 fp32: out[n][f] = ybuf[n*64+yOff+f] + sum w*z[s*zStride+zOff+f] ----
__device__ __forceinline__ void hop10_phase(const float* __restrict__ z, int zStride, int zOff,
                                            const float* __restrict__ ybuf, int yOff,
                                            const int* __restrict__ ptr, const int* __restrict__ srcs,
                                            const float* __restrict__ wsrt, float* __restrict__ outp) {
  const int lane = threadIdx.x & 63;
  const int wid = threadIdx.x >> 6;
  const int sub = lane >> 4;
  const int f = lane & 15;
  for (int node = blockIdx.x * 4 + wid; node < N_NODES; node += gridDim.x * 4) {
    const int b = ptr[node], e = ptr[node + 1];
    const int len = e - b;
    const int js = b + (len * sub) / 4;
    const int je = b + (len * (sub + 1)) / 4;
    float acc = 0.f;
    if (f < CDIM) {
      if (sub == 0) acc = ybuf[(size_t)node * 64 + yOff + f];
      int j = js;
      for (; j + 1 < je; j += 2) {
        int s0 = srcs[j], s1 = srcs[j + 1];
        float w0 = wsrt[j], w1 = wsrt[j + 1];
        acc += w0 * z[(size_t)s0 * zStride + zOff + f] + w1 * z[(size_t)s1 * zStride + zOff + f];
      }
      if (j < je) acc += wsrt[j] * z[(size_t)srcs[j] * zStride + zOff + f];
    }
    acc += __shfl_xor(acc, 16);
    acc += __shfl_xor(acc, 32);
    if (sub == 0 && f < CDIM) outp[(size_t)node * CDIM + f] = acc;
  }
}

// ================= the mega kernel =================
__global__ __launch_bounds__(256, 4) void mega_kernel(MegaArgs a) {
  cg::grid_group g = cg::this_grid();
  __shared__ float xt[32][68];
  __shared__ float bt[32][64];
  __shared__ int sdi[256];
  const int tid = threadIdx.x;
  const int gtid = blockIdx.x * blockDim.x + tid;
  const int gstride = gridDim.x * blockDim.x;
  const int TG0 = ((N_NODES + 63) / 64) * 2;   // 1564
  const int TG1 = (N_NODES + 63) / 64;         // 782

  // P0: zero deg/cnt
  for (int i = gtid; i < N_NODES; i += gstride) { a.deg[i] = 0.f; a.cnt[i] = 0; }
  g.sync();

  // P1: convert edges + degree atomics
  {
    bool is64 = true;
    for (int i = 0; i < 32; ++i) if (a.ei[2 * i + 1] != 0) is64 = false;
    for (int e = gtid; e < N_EDGES; e += gstride) {
      int r, c;
      if (is64) { r = a.ei[2 * e]; c = a.ei[2 * (N_EDGES + e)]; }
      else      { r = a.ei[e];     c = a.ei[N_EDGES + e]; }
      a.row32[e] = r; a.col32[e] = c;
      atomicAdd(&a.deg[c], a.ew[e]);
      atomicAdd(&a.cnt[c], 1);
    }
  }
  g.sync();

  // P2: dis + per-chunk count sums
  for (int i = gtid; i < N_NODES; i += gstride) {
    float d = a.deg[i];
    a.dis[i] = d > 0.f ? rsqrtf(fmaxf(d, 1e-12f)) : 0.f;
  }
  for (int c = blockIdx.x; c < NCH; c += gridDim.x) {
    int i = c * 256 + tid;
    sdi[tid] = (i < N_NODES) ? a.cnt[i] : 0;
    __syncthreads();
    for (int s = 128; s > 0; s >>= 1) { if (tid < s) sdi[tid] += sdi[tid + s]; __syncthreads(); }
    if (tid == 0) a.part[c] = sdi[0];
    __syncthreads();
  }
  g.sync();

  // P3: block 0: exclusive scan of partials, total -> ptrA[N]
  if (blockIdx.x == 0) {
    int v = (tid < NCH) ? a.part[tid] : 0;
    sdi[tid] = v;
    __syncthreads();
    for (int o = 1; o < 256; o <<= 1) {
      int t2 = (tid >= o) ? sdi[tid - o] : 0;
      __syncthreads();
      sdi[tid] += t2;
      __syncthreads();
    }
    if (tid < NCH) a.part[tid] = sdi[tid] - v;
    if (tid == 255) a.ptrA[N_NODES] = sdi[255];
  }
  g.sync();

  // P4: per-chunk exclusive scan -> ptr, pos
  for (int c = blockIdx.x; c < NCH; c += gridDim.x) {
    int i = c * 256 + tid;
    int v = (i < N_NODES) ? a.cnt[i] : 0;
    sdi[tid] = v;
    __syncthreads();
    for (int o = 1; o < 256; o <<= 1) {
      int t2 = (tid >= o) ? sdi[tid - o] : 0;
      __syncthreads();
      sdi[tid] += t2;
      __syncthreads();
    }
    if (i < N_NODES) { int p = a.part[c] + sdi[tid] - v; a.ptrA[i] = p; a.pos[i] = p; }
    __syncthreads();
  }
  g.sync();

  // P5: place into CSC + fused norm
  for (int e = gtid; e < N_EDGES; e += gstride) {
    int r = a.row32[e], c = a.col32[e];
    int slot = atomicAdd(&a.pos[c], 1);
    a.srcs[slot] = r;
    a.wsrt[slot] = a.dis[r] * a.ew[e] * a.dis[c];
  }
  g.sync();

  // ===== layer 1 (in = x, K=100): serial Horner, bufs A,B,C =====
  for (int t = blockIdx.x; t < TG0; t += gridDim.x)
    gemm_tile<F_IN_D, 0, false>(a.x, a.W1 + (size_t)5 * F_IN_D * 128, a.b1, a.B, t, xt, bt);
  for (int t = blockIdx.x; t < TG0; t += gridDim.x)
    gemm_tile<F_IN_D, 0, false>(a.x, a.W1 + (size_t)4 * F_IN_D * 128, a.b1, a.A, t, xt, bt);
  g.sync();
  hop128_phase<false>(a.B, a.A, a.ptrA, a.srcs, a.wsrt, a.C); g.sync();
  for (int t = blockIdx.x; t < TG0; t += gridDim.x)
    gemm_tile<F_IN_D, 0, false>(a.x, a.W1 + (size_t)3 * F_IN_D * 128, a.b1, a.A, t, xt, bt);
  g.sync();
  hop128_phase<false>(a.C, a.A, a.ptrA, a.srcs, a.wsrt, a.B); g.sync();
  for (int t = blockIdx.x; t < TG0; t += gridDim.x)
    gemm_tile<F_IN_D, 0, false>(a.x, a.W1 + (size_t)2 * F_IN_D * 128, a.b1, a.A, t, xt, bt);
  g.sync();
  hop128_phase<false>(a.B, a.A, a.ptrA, a.srcs, a.wsrt, a.C); g.sync();
  for (int t = blockIdx.x; t < TG0; t += gridDim.x)
    gemm_tile<F_IN_D, 0, false>(a.x, a.W1 + (size_t)1 * F_IN_D * 128, a.b1, a.A, t, xt, bt);
  g.sync();
  hop128_phase<false>(a.C, a.A, a.ptrA, a.srcs, a.wsrt, a.B); g.sync();
  for (int t = blockIdx.x; t < TG0; t += gridDim.x)
    gemm_tile<F_IN_D, 0, true>(a.x, a.W1, a.b1, a.A, t, xt, bt);
  g.sync();
  hop128_phase<true>(a.B, a.A, a.ptrA, a.srcs, a.wsrt, a.C); g.sync();
  // h1 = C

  // ===== layer 2 (in = C, K=128): bufs A,B,D =====
  for (int t = blockIdx.x; t < TG0; t += gridDim.x)
    gemm_tile<HDIM, 0, false>(a.C, a.W2 + (size_t)5 * HDIM * 128, a.b2, a.B, t, xt, bt);
  for (int t = blockIdx.x; t < TG0; t += gridDim.x)
    gemm_tile<HDIM, 0, false>(a.C, a.W2 + (size_t)4 * HDIM * 128, a.b2, a.A, t, xt, bt);
  g.sync();
  hop128_phase<false>(a.B, a.A, a.ptrA, a.srcs, a.wsrt, a.D); g.sync();
  for (int t = blockIdx.x; t < TG0; t += gridDim.x)
    gemm_tile<HDIM, 0, false>(a.C, a.W2 + (size_t)3 * HDIM * 128, a.b2, a.A, t, xt, bt);
  g.sync();
  hop128_phase<false>(a.D, a.A, a.ptrA, a.srcs, a.wsrt, a.B); g.sync();
  for (int t = blockIdx.x; t < TG0; t += gridDim.x)
    gemm_tile<HDIM, 0, false>(a.C, a.W2 + (size_t)2 * HDIM * 128, a.b2, a.A, t, xt, bt);
  g.sync();
  hop128_phase<false>(a.B, a.A, a.ptrA, a.srcs, a.wsrt, a.D); g.sync();
  for (int t = blockIdx.x; t < TG0; t += gridDim.x)
    gemm_tile<HDIM, 0, false>(a.C, a.W2 + (size_t)1 * HDIM * 128, a.b2, a.A, t, xt, bt);
  g.sync();
  hop128_phase<false>(a.D, a.A, a.ptrA, a.srcs, a.wsrt, a.B); g.sync();
  for (int t = blockIdx.x; t < TG0; t += gridDim.x)
    gemm_tile<HDIM, 0, true>(a.C, a.W2, a.b2, a.A, t, xt, bt);
  g.sync();
  hop128_phase<true>(a.B, a.A, a.ptrA, a.srcs, a.wsrt, a.D); g.sync();
  // h2 = D

  // ===== layer 3 (in = D): ybuf = A [N][64], z0/z1 in B/C =====
  for (int t = blockIdx.x; t < TG1; t += gridDim.x)
    gemm_tile<HDIM, 1, true>(a.D, a.W3, a.b3, a.A, t, xt, bt);
  g.sync();
  hop10_phase(a.A, 64, 50, a.A, 40, a.ptrA, a.srcs, a.wsrt, a.B); g.sync();
  hop10_phase(a.B, 10, 0, a.A, 30, a.ptrA, a.srcs, a.wsrt, a.C); g.sync();
  hop10_phase(a.C, 10, 0, a.A, 20, a.ptrA, a.srcs, a.wsrt, a.B); g.sync();
  hop10_phase(a.B, 10, 0, a.A, 10, a.ptrA, a.srcs, a.wsrt, a.C); g.sync();
  hop10_phase(a.C, 10, 0, a.A, 0, a.ptrA, a.srcs, a.wsrt, a.out);
}

// ---------------- host ----------------

extern "C" void kernel_launch(void* const* d_in, const int* in_sizes, int n_in,
                              void* d_out, int out_size, void* d_ws, size_t ws_size,
                              hipStream_t stream) {
  MegaArgs a;
  a.x  = (const float*)d_in[0];
  a.ei = (const int*)d_in[1];
  a.ew = (const float*)d_in[2];
  a.W1 = (const float*)d_in[3];
  a.b1 = (const float*)d_in[4];
  a.W2 = (const float*)d_in[5];
  a.b2 = (const float*)d_in[6];
  a.W3 = (const float*)d_in[7];
  a.b3 = (const float*)d_in[8];
  a.out = (float*)d_out;

  const int N = N_NODES, E = N_EDGES;
  char* base = (char*)d_ws;
  size_t off = 0;
  auto alloc = [&](size_t bytes) -> char* {
    char* p = base + off;
    off += (bytes + 255) & ~(size_t)255;
    return p;
  };
  a.A = (float*)alloc((size_t)N * 128 * 4);
  a.B = (float*)alloc((size_t)N * 128 * 4);
  a.C = (float*)alloc((size_t)N * 128 * 4);
  a.D = (float*)alloc((size_t)N * 128 * 4);
  a.ptrA = (int*)alloc((size_t)(N + 1) * 4);
  a.pos  = (int*)alloc((size_t)N * 4);
  a.srcs = (int*)alloc((size_t)E * 4);
  a.wsrt = (float*)alloc((size_t)E * 4);

  // Prep transients overlay D (row32/col32; D first written in layer 2)
  a.row32 = (int*)a.D;
  a.col32 = (int*)a.D + E;
  // deg/dis/cnt/part overlay C (C first written in layer-1 hop, after prep)
  a.deg  = (float*)a.C;
  a.dis  = (float*)a.C + N;
  a.cnt  = (int*)((float*)a.C + 2 * N);
  a.part = (int*)((float*)a.C + 3 * N);

  int occ = 0;
  hipOccupancyMaxActiveBlocksPerMultiprocessor(&occ, (const void*)mega_kernel, 256, 0);
  int grid = occ * 256;           // 256 CUs on MI355X
  if (grid > 1024) grid = 1024;   // cap: 4 blocks/CU by __launch_bounds__
  if (grid < 64) grid = 64;       // paranoia floor (co-residency always >= this)

  void* args[] = { &a };
  hipLaunchCooperativeKernel((const void*)mega_kernel, dim3(grid), dim3(256), args, 0, stream);

  (void)in_sizes; (void)n_in; (void)out_size; (void)ws_size;
}

// Round 9
// 13284.027 us; speedup vs baseline: 1.1970x; 1.1970x over previous
//
#include <hip/hip_runtime.h>
#include <cstdint>
#include <cstddef>

#define N_NODES 50000
#define N_EDGES 800000
#define F_IN_D 100
#define HDIM 128
#define CDIM 10
#define NSLAB 8
#define SLABN (N_NODES / NSLAB)          // 6250 nodes * 512 B = 3.2 MB < 4 MB L2/XCD
#define NKEY (NSLAB * N_NODES)           // 400000 (slab,dest) bins

typedef unsigned short ushortT;

__device__ __forceinline__ float bf2f(unsigned int b16) {
  return __uint_as_float(b16 << 16);
}
__device__ __forceinline__ unsigned int f2bf(float f) {   // RNE bf16
  unsigned int u = __float_as_uint(f);
  unsigned int r = u + 0x7FFFu + ((u >> 16) & 1u);
  return r >> 16;
}

// ---------------- preprocessing ----------------

// convert + dest-degree atomics + dest-count + (slab,dest)-count in one pass
__global__ void prep_convert_kernel(const int* __restrict__ ei, const float* __restrict__ ew,
                                    int* __restrict__ row32, int* __restrict__ col32,
                                    float* __restrict__ deg, int* __restrict__ cnt,
                                    int* __restrict__ cnt2, int E, int doSlab) {
  bool is64 = true;
  for (int i = 0; i < 32; ++i) { if (ei[2 * i + 1] != 0) is64 = false; }
  int e = blockIdx.x * blockDim.x + threadIdx.x;
  if (e < E) {
    int r, c;
    if (is64) { r = ei[2 * e]; c = ei[2 * (E + e)]; }
    else      { r = ei[e];     c = ei[E + e]; }
    row32[e] = r; col32[e] = c;
    atomicAdd(&deg[c], ew[e]);
    atomicAdd(&cnt[c], 1);
    if (doSlab) atomicAdd(&cnt2[(r / SLABN) * N_NODES + c], 1);
  }
}

__global__ void prep_dis_kernel(const float* __restrict__ deg, float* __restrict__ dis, int n) {
  int i = blockIdx.x * blockDim.x + threadIdx.x;
  if (i < n) {
    float d = deg[i];
    dis[i] = d > 0.f ? rsqrtf(fmaxf(d, 1e-12f)) : 0.f;
  }
}

// block sums of cnt chunks (256 elems/block)
__global__ void prep_scanA_kernel(const int* __restrict__ cnt, int* __restrict__ partial, int n) {
  __shared__ int sd[256];
  int tid = threadIdx.x;
  int i = blockIdx.x * 256 + tid;
  sd[tid] = (i < n) ? cnt[i] : 0;
  __syncthreads();
  for (int s = 128; s > 0; s >>= 1) {
    if (tid < s) sd[tid] += sd[tid + s];
    __syncthreads();
  }
  if (tid == 0) partial[blockIdx.x] = sd[0];
}

// exclusive scan of block partials (any nb, chunked with carry), plus ptr[n] = total
__global__ void prep_scanB_kernel(int* __restrict__ partial, int* __restrict__ ptr, int nb, int n) {
  __shared__ int sd[256];
  __shared__ int carry;
  int tid = threadIdx.x;
  if (tid == 0) carry = 0;
  __syncthreads();
  for (int base = 0; base < nb; base += 256) {
    int i = base + tid;
    int v = (i < nb) ? partial[i] : 0;
    sd[tid] = v;
    __syncthreads();
    for (int o = 1; o < 256; o <<= 1) {
      int t = (tid >= o) ? sd[tid - o] : 0;
      __syncthreads();
      sd[tid] += t;
      __syncthreads();
    }
    if (i < nb) partial[i] = carry + sd[tid] - v;
    int tot = sd[255];
    __syncthreads();
    if (tid == 0) carry += tot;
    __syncthreads();
  }
  if (tid == 0) ptr[n] = carry;
}

// per-chunk exclusive scan + block offset -> ptr, pos
__global__ void prep_scanC_kernel(const int* __restrict__ cnt, const int* __restrict__ partial,
                                  int* __restrict__ ptr, int* __restrict__ pos, int n) {
  __shared__ int sd[256];
  int tid = threadIdx.x;
  int i = blockIdx.x * 256 + tid;
  int v = (i < n) ? cnt[i] : 0;
  sd[tid] = v;
  __syncthreads();
  for (int o = 1; o < 256; o <<= 1) {
    int t = (tid >= o) ? sd[tid - o] : 0;
    __syncthreads();
    sd[tid] += t;
    __syncthreads();
  }
  if (i < n) {
    int p = partial[blockIdx.x] + sd[tid] - v;
    ptr[i] = p;
    pos[i] = p;
  }
}

// dest-major CSC place (+ fused norm) — used by hop10 (and fallback hop128)
__global__ void prep_place_kernel(const int* __restrict__ row32, const int* __restrict__ col32,
                                  const float* __restrict__ ew, const float* __restrict__ dis,
                                  int* __restrict__ pos, int* __restrict__ srcs,
                                  float* __restrict__ wsrt, int E) {
  int e = blockIdx.x * blockDim.x + threadIdx.x;
  if (e < E) {
    int r = row32[e], c = col32[e];
    int slot = atomicAdd(&pos[c], 1);
    srcs[slot] = r;
    wsrt[slot] = dis[r] * ew[e] * dis[c];
  }
}

// (slab,dest)-major place (+ fused norm) — used by hop_slab
__global__ void prep_place2_kernel(const int* __restrict__ row32, const int* __restrict__ col32,
                                   const float* __restrict__ ew, const float* __restrict__ dis,
                                   int* __restrict__ pos2, int* __restrict__ srcs2,
                                   float* __restrict__ wsrt2, int E) {
  int e = blockIdx.x * blockDim.x + threadIdx.x;
  if (e < E) {
    int r = row32[e], c = col32[e];
    int key = (r / SLABN) * N_NODES + c;
    int slot = atomicAdd(&pos2[key], 1);
    srcs2[slot] = r;
    wsrt2[slot] = dis[r] * ew[e] * dis[c];
  }
}

// ---------------- slab hop (d=128) ----------------
// Pass 1: blocks with blockIdx.x%8==s process only slab-s edges; all gathers fall in
// the 3.2-MB slab of P -> per-XCD L2-resident. Writes bf16 partial rows PT[s][n][128]
// unconditionally (zeros for empty segments), so no zero-init needed.
template <int TAG>
__global__ void hop_slab_kernel(const float* __restrict__ P, ushortT* __restrict__ PT,
                                const int* __restrict__ ptr2, const int* __restrict__ srcs2,
                                const float* __restrict__ wsrt2) {
  const int lane = threadIdx.x & 63;
  const int wid = threadIdx.x >> 6;            // 4 waves/block
  const int grp = lane >> 5;                   // 2 edge groups
  const int f4 = lane & 31;                    // float4 slot: 32 x 4 = 128 feats
  const int s = blockIdx.x & 7;                // slab == XCD (blockIdx%8 swizzle)
  const int bs = blockIdx.x >> 3;
  const int wavesPerSlab = (gridDim.x >> 3) * 4;
  const float4* P4 = (const float4*)P;
  for (int n = bs * 4 + wid; n < N_NODES; n += wavesPerSlab) {
    const int key = s * N_NODES + n;
    const int b = ptr2[key], e = ptr2[key + 1];
    float4 acc = make_float4(0.f, 0.f, 0.f, 0.f);
    for (int j = b + grp; j < e; j += 2) {
      const int src = srcs2[j];
      const float w = wsrt2[j];
      float4 v = P4[(size_t)src * 32 + f4];
      acc.x += w * v.x; acc.y += w * v.y; acc.z += w * v.z; acc.w += w * v.w;
    }
    acc.x += __shfl_xor(acc.x, 32);
    acc.y += __shfl_xor(acc.y, 32);
    acc.z += __shfl_xor(acc.z, 32);
    acc.w += __shfl_xor(acc.w, 32);
    if (grp == 0) {
      uint2 o;
      o.x = f2bf(acc.x) | (f2bf(acc.y) << 16);
      o.y = f2bf(acc.z) | (f2bf(acc.w) << 16);
      ((uint2*)PT)[((size_t)s * N_NODES + n) * 32 + f4] = o;
    }
  }
}

// Pass 2: Q[n] = maybeELU( Y[n] + sum_s PT[s][n] )  — streaming, fixed order, deterministic
template <int TAG, bool ELU>
__global__ void hop_reduce_kernel(const ushortT* __restrict__ PT, const float* __restrict__ Y,
                                  float* __restrict__ Q, int n) {
  const int f4 = threadIdx.x & 31;
  const int ln = threadIdx.x >> 5;             // 8 nodes / 256-thread block
  int node = blockIdx.x * 8 + ln;
  if (node >= n) return;
  float4 acc = ((const float4*)Y)[(size_t)node * 32 + f4];
  const uint2* PT2 = (const uint2*)PT;
#pragma unroll
  for (int s = 0; s < NSLAB; ++s) {
    uint2 v = PT2[((size_t)s * N_NODES + node) * 32 + f4];
    acc.x += bf2f(v.x & 0xFFFFu);
    acc.y += bf2f(v.x >> 16);
    acc.z += bf2f(v.y & 0xFFFFu);
    acc.w += bf2f(v.y >> 16);
  }
  if (ELU) {
    acc.x = acc.x > 0.f ? acc.x : expm1f(acc.x);
    acc.y = acc.y > 0.f ? acc.y : expm1f(acc.y);
    acc.z = acc.z > 0.f ? acc.z : expm1f(acc.z);
    acc.w = acc.w > 0.f ? acc.w : expm1f(acc.w);
  }
  ((float4*)Q)[(size_t)node * 32 + f4] = acc;
}

// ---------------- fallback hop d=128 (R6 version) ----------------
template <int TAG, bool ELU>
__global__ void hop128_kernel(const float* __restrict__ sin_, const float* __restrict__ y,
                              const int* __restrict__ ptr, const int* __restrict__ srcs,
                              const float* __restrict__ w, float* __restrict__ sout, int n) {
  const int lane = threadIdx.x & 63;
  const int wid = threadIdx.x >> 6;
  const int half = lane >> 5;
  const int f4 = lane & 31;
  const int node = blockIdx.x * 4 + wid;
  if (node >= n) return;
  const float4* s4 = (const float4*)sin_;
  const int b = ptr[node], e = ptr[node + 1];
  const int len = e - b;
  const int c0 = (len + 1) >> 1;
  const int js = half ? (b + c0) : b;
  const int je = half ? e : (b + c0);
  float4 acc;
  if (half == 0) acc = ((const float4*)y)[(size_t)node * 32 + f4];
  else           acc = make_float4(0.f, 0.f, 0.f, 0.f);
  for (int j = js; j < je; ++j) {
    float w0 = w[j];
    float4 v0 = s4[(size_t)srcs[j] * 32 + f4];
    acc.x += w0 * v0.x; acc.y += w0 * v0.y; acc.z += w0 * v0.z; acc.w += w0 * v0.w;
  }
  acc.x += __shfl_xor(acc.x, 32);
  acc.y += __shfl_xor(acc.y, 32);
  acc.z += __shfl_xor(acc.z, 32);
  acc.w += __shfl_xor(acc.w, 32);
  if (half == 0) {
    if (ELU) {
      acc.x = acc.x > 0.f ? acc.x : expm1f(acc.x);
      acc.y = acc.y > 0.f ? acc.y : expm1f(acc.y);
      acc.z = acc.z > 0.f ? acc.z : expm1f(acc.z);
      acc.w = acc.w > 0.f ? acc.w : expm1f(acc.w);
    }
    ((float4*)sout)[(size_t)node * 32 + f4] = acc;
  }
}

// ---------------- hop d=10 (dest-major CSC; working set 2 MB = L2-resident) ----------------
template <int TAG>
__global__ void hop10_kernel(const float* __restrict__ z, int zStride, int zOff,
                             const float* __restrict__ ybuf, int yOff,
                             const int* __restrict__ ptr, const int* __restrict__ srcs,
                             const float* __restrict__ wsrt, float* __restrict__ out, int n) {
  const int lane = threadIdx.x & 63;
  const int wid = threadIdx.x >> 6;
  const int sub = lane >> 4;
  const int f = lane & 15;
  const int node = blockIdx.x * 4 + wid;
  if (node >= n) return;
  const int b = ptr[node], e = ptr[node + 1];
  const int len = e - b;
  const int js = b + (len * sub) / 4;
  const int je = b + (len * (sub + 1)) / 4;
  float acc = 0.f;
  if (f < CDIM) {
    if (sub == 0) acc = ybuf[(size_t)node * 64 + yOff + f];
    for (int j = js; j < je; ++j)
      acc += wsrt[j] * z[(size_t)srcs[j] * zStride + zOff + f];
  }
  acc += __shfl_xor(acc, 16);
  acc += __shfl_xor(acc, 32);
  if (sub == 0 && f < CDIM) out[(size_t)node * CDIM + f] = acc;
}

// ---------------- dense GEMM (fp32, R5-proven) ----------------
template <int TAG, int K_DIM, int BMODE, bool ADD_BIAS>
__global__ void gemm_kernel(const float* __restrict__ X, const float* __restrict__ W,
                            const float* __restrict__ bias, float* __restrict__ out,
                            int n, int ostride) {
  __shared__ float xt[32][68];
  __shared__ float bt[32][64];
  const int tid = threadIdx.x;
  const int tx = tid & 15;
  const int ty = tid >> 4;
  const int n0 = blockIdx.x * 64;
  const int c0 = blockIdx.y * 64;
  float acc[4][4];
#pragma unroll
  for (int i = 0; i < 4; ++i)
#pragma unroll
    for (int j = 0; j < 4; ++j) acc[i][j] = 0.f;

  for (int k0 = 0; k0 < K_DIM; k0 += 32) {
#pragma unroll
    for (int i = 0; i < 8; ++i) {
      int idx = tid + i * 256;
      int nl = idx >> 5, kl = idx & 31;
      int nn = n0 + nl, kg = k0 + kl;
      float v = 0.f;
      if (nn < n && kg < K_DIM) v = X[(size_t)nn * K_DIM + kg];
      xt[kl][nl] = v;
    }
#pragma unroll
    for (int i = 0; i < 8; ++i) {
      int idx = tid + i * 256;
      int kl = idx >> 6, cl = idx & 63;
      int kg = k0 + kl, c = c0 + cl;
      float v = 0.f;
      if (BMODE == 0) {
        if (kg < K_DIM) v = W[(size_t)kg * 128 + c];
      } else {
        if (kg < K_DIM && cl < 6 * CDIM)
          v = W[(size_t)(cl / CDIM) * (K_DIM * CDIM) + (size_t)kg * CDIM + (cl % CDIM)];
      }
      bt[kl][cl] = v;
    }
    __syncthreads();
#pragma unroll
    for (int kk = 0; kk < 32; ++kk) {
      float4 xv = *(const float4*)&xt[kk][tx * 4];
      float4 bv = *(const float4*)&bt[kk][ty * 4];
      acc[0][0] += xv.x * bv.x; acc[0][1] += xv.x * bv.y; acc[0][2] += xv.x * bv.z; acc[0][3] += xv.x * bv.w;
      acc[1][0] += xv.y * bv.x; acc[1][1] += xv.y * bv.y; acc[1][2] += xv.y * bv.z; acc[1][3] += xv.y * bv.w;
      acc[2][0] += xv.z * bv.x; acc[2][1] += xv.z * bv.y; acc[2][2] += xv.z * bv.z; acc[2][3] += xv.z * bv.w;
      acc[3][0] += xv.w * bv.x; acc[3][1] += xv.w * bv.y; acc[3][2] += xv.w * bv.z; acc[3][3] += xv.w * bv.w;
    }
    __syncthreads();
  }
#pragma unroll
  for (int i = 0; i < 4; ++i) {
    int nn = n0 + tx * 4 + i;
    if (nn >= n) continue;
#pragma unroll
    for (int j = 0; j < 4; ++j) {
      int c = c0 + ty * 4 + j;
      float r = acc[i][j];
      if (ADD_BIAS) {
        if (BMODE == 0) r += bias[c];
        else if (c < CDIM) r += bias[c];
      }
      out[(size_t)nn * ostride + c] = r;
    }
  }
}

// ---------------- host ----------------

extern "C" void kernel_launch(void* const* d_in, const int* in_sizes, int n_in,
                              void* d_out, int out_size, void* d_ws, size_t ws_size,
                              hipStream_t stream) {
  const float* x  = (const float*)d_in[0];
  const int*   ei = (const int*)d_in[1];
  const float* ew = (const float*)d_in[2];
  const float* W1 = (const float*)d_in[3];
  const float* b1 = (const float*)d_in[4];
  const float* W2 = (const float*)d_in[5];
  const float* b2 = (const float*)d_in[6];
  const float* W3 = (const float*)d_in[7];
  const float* b3 = (const float*)d_in[8];
  float* out = (float*)d_out;

  const int N = N_NODES, E = N_EDGES;
  char* base = (char*)d_ws;
  size_t off = 0;
  auto alloc = [&](size_t bytes) -> char* {
    char* p = base + off;
    off += (bytes + 255) & ~(size_t)255;
    return p;
  };
  // common buffers
  float* A = (float*)alloc((size_t)N * 128 * 4);
  float* B = (float*)alloc((size_t)N * 128 * 4);
  float* C = (float*)alloc((size_t)N * 128 * 4);
  float* D = (float*)alloc((size_t)N * 128 * 4);
  int*   ptrA = (int*)alloc((size_t)(N + 1) * 4);
  int*   pos  = (int*)alloc((size_t)N * 4);
  int*   srcs = (int*)alloc((size_t)E * 4);
  float* wsrt = (float*)alloc((size_t)E * 4);
  size_t off_common = off;

  // slab-path extras
  ushortT* PT   = (ushortT*)alloc((size_t)NSLAB * N * 128 * 2);   // 102.4 MB
  int*   srcs2  = (int*)alloc((size_t)E * 4);
  float* wsrt2  = (float*)alloc((size_t)E * 4);
  int*   ptr2   = (int*)alloc((size_t)(NKEY + 1) * 4);
  int*   pos2   = (int*)alloc((size_t)NKEY * 4);
  bool slabOK = (off <= ws_size);

  // prep transients: slab path -> overlay PT (first written in first hop);
  // fallback -> overlay A (first written by 2nd GEMM, after prep).
  char* tbase = slabOK ? (char*)PT : (char*)A;
  int*   row32 = (int*)tbase;                 tbase += (size_t)E * 4;
  int*   col32 = (int*)tbase;                 tbase += (size_t)E * 4;
  float* deg   = (float*)tbase;               tbase += (size_t)N * 4;
  float* dis   = (float*)tbase;               tbase += (size_t)N * 4;
  int*   cnt   = (int*)tbase;                 tbase += (size_t)N * 4;
  int*   part  = (int*)tbase;                 tbase += 2048 * 4;
  int*   cnt2  = (int*)tbase;                 tbase += (size_t)NKEY * 4;   // slab only
  int*   part2 = (int*)tbase;                 tbase += 2048 * 4;           // slab only

  const int eb  = (E + 255) / 256;
  const int nb  = (N + 255) / 256;        // 196
  const int nb2 = (NKEY + 255) / 256;     // 1563

  hipMemsetAsync(deg, 0, (size_t)N * 4, stream);
  hipMemsetAsync(cnt, 0, (size_t)N * 4, stream);
  if (slabOK) hipMemsetAsync(cnt2, 0, (size_t)NKEY * 4, stream);

  prep_convert_kernel<<<eb, 256, 0, stream>>>(ei, ew, row32, col32, deg, cnt, cnt2, E, slabOK ? 1 : 0);
  prep_dis_kernel<<<nb, 256, 0, stream>>>(deg, dis, N);
  prep_scanA_kernel<<<nb, 256, 0, stream>>>(cnt, part, N);
  prep_scanB_kernel<<<1, 256, 0, stream>>>(part, ptrA, nb, N);
  prep_scanC_kernel<<<nb, 256, 0, stream>>>(cnt, part, ptrA, pos, N);
  prep_place_kernel<<<eb, 256, 0, stream>>>(row32, col32, ew, dis, pos, srcs, wsrt, E);
  if (slabOK) {
    prep_scanA_kernel<<<nb2, 256, 0, stream>>>(cnt2, part2, NKEY);
    prep_scanB_kernel<<<1, 256, 0, stream>>>(part2, ptr2, nb2, NKEY);
    prep_scanC_kernel<<<nb2, 256, 0, stream>>>(cnt2, part2, ptr2, pos2, NKEY);
    prep_place2_kernel<<<eb, 256, 0, stream>>>(row32, col32, ew, dis, pos2, srcs2, wsrt2, E);
  }

  const dim3 gemmGrid((N + 63) / 64, 2);
  const int hopBlocks = (N + 3) / 4;
  const int slabGrid = NSLAB * 256;            // 256 blocks per slab/XCD
  const int redGrid = (N + 7) / 8;

  // hop dispatch helper: P,Y -> Q
  auto HOP = [&](const float* P, const float* Y, float* Q, bool elu, int tag) {
    if (slabOK) {
      switch (tag) {   // TAG only for profiler attribution
        case 0: hop_slab_kernel<0><<<slabGrid, 256, 0, stream>>>(P, PT, ptr2, srcs2, wsrt2); break;
        case 1: hop_slab_kernel<1><<<slabGrid, 256, 0, stream>>>(P, PT, ptr2, srcs2, wsrt2); break;
        default: hop_slab_kernel<2><<<slabGrid, 256, 0, stream>>>(P, PT, ptr2, srcs2, wsrt2); break;
      }
      if (elu) hop_reduce_kernel<0, true><<<redGrid, 256, 0, stream>>>(PT, Y, Q, N);
      else     hop_reduce_kernel<0, false><<<redGrid, 256, 0, stream>>>(PT, Y, Q, N);
    } else {
      if (elu) hop128_kernel<0, true><<<hopBlocks, 256, 0, stream>>>(P, Y, ptrA, srcs, wsrt, Q, N);
      else     hop128_kernel<0, false><<<hopBlocks, 256, 0, stream>>>(P, Y, ptrA, srcs, wsrt, Q, N);
    }
  };

  // ===== layer 1 (in = x, K=100): Horner s=y5; s=A*s+y_k; ELU at k=0.  result -> C =====
  gemm_kernel<15, F_IN_D, 0, false><<<gemmGrid, 256, 0, stream>>>(x, W1 + (size_t)5 * F_IN_D * 128, b1, B, N, 128);
  gemm_kernel<14, F_IN_D, 0, false><<<gemmGrid, 256, 0, stream>>>(x, W1 + (size_t)4 * F_IN_D * 128, b1, A, N, 128);
  HOP(B, A, C, false, 0);
  gemm_kernel<13, F_IN_D, 0, false><<<gemmGrid, 256, 0, stream>>>(x, W1 + (size_t)3 * F_IN_D * 128, b1, A, N, 128);
  HOP(C, A, B, false, 1);
  gemm_kernel<12, F_IN_D, 0, false><<<gemmGrid, 256, 0, stream>>>(x, W1 + (size_t)2 * F_IN_D * 128, b1, A, N, 128);
  HOP(B, A, C, false, 2);
  gemm_kernel<11, F_IN_D, 0, false><<<gemmGrid, 256, 0, stream>>>(x, W1 + (size_t)1 * F_IN_D * 128, b1, A, N, 128);
  HOP(C, A, B, false, 0);
  gemm_kernel<10, F_IN_D, 0, true><<<gemmGrid, 256, 0, stream>>>(x, W1, b1, A, N, 128);
  HOP(B, A, C, true, 1);
  // h1 = C

  // ===== layer 2 (in = C, K=128): result -> D =====
  gemm_kernel<25, HDIM, 0, false><<<gemmGrid, 256, 0, stream>>>(C, W2 + (size_t)5 * HDIM * 128, b2, B, N, 128);
  gemm_kernel<24, HDIM, 0, false><<<gemmGrid, 256, 0, stream>>>(C, W2 + (size_t)4 * HDIM * 128, b2, A, N, 128);
  HOP(B, A, D, false, 2);
  gemm_kernel<23, HDIM, 0, false><<<gemmGrid, 256, 0, stream>>>(C, W2 + (size_t)3 * HDIM * 128, b2, A, N, 128);
  HOP(D, A, B, false, 0);
  gemm_kernel<22, HDIM, 0, false><<<gemmGrid, 256, 0, stream>>>(C, W2 + (size_t)2 * HDIM * 128, b2, A, N, 128);
  HOP(B, A, D, false, 1);
  gemm_kernel<21, HDIM, 0, false><<<gemmGrid, 256, 0, stream>>>(C, W2 + (size_t)1 * HDIM * 128, b2, A, N, 128);
  HOP(D, A, B, false, 2);
  gemm_kernel<20, HDIM, 0, true><<<gemmGrid, 256, 0, stream>>>(C, W2, b2, A, N, 128);
  HOP(B, A, D, true, 0);
  // h2 = D

  // ===== layer 3 (in = D): ybuf = A [N][64]; z0/z1 slices of B =====
  {
    float* ybuf = A;
    float* z0 = B;
    float* z1 = (float*)((char*)B + (size_t)N * 16 * 4);
    dim3 g3((N + 63) / 64, 1);
    gemm_kernel<30, HDIM, 1, true><<<g3, 256, 0, stream>>>(D, W3, b3, ybuf, N, 64);
    hop10_kernel<35><<<hopBlocks, 256, 0, stream>>>(ybuf, 64, 50, ybuf, 40, ptrA, srcs, wsrt, z0, N);
    hop10_kernel<34><<<hopBlocks, 256, 0, stream>>>(z0, 10, 0, ybuf, 30, ptrA, srcs, wsrt, z1, N);
    hop10_kernel<33><<<hopBlocks, 256, 0, stream>>>(z1, 10, 0, ybuf, 20, ptrA, srcs, wsrt, z0, N);
    hop10_kernel<32><<<hopBlocks, 256, 0, stream>>>(z0, 10, 0, ybuf, 10, ptrA, srcs, wsrt, z1, N);
    hop10_kernel<31><<<hopBlocks, 256, 0, stream>>>(z1, 10, 0, ybuf, 0, ptrA, srcs, wsrt, out, N);
  }

  (void)in_sizes; (void)n_in; (void)out_size; (void)off_common;
}

// Round 10
// 11247.036 us; speedup vs baseline: 1.4138x; 1.1811x over previous
//
#include <hip/hip_runtime.h>
#include <cstdint>
#include <cstddef>

#define N_NODES 50000
#define N_EDGES 800000
#define F_IN_D 100
#define HDIM 128
#define CDIM 10
#define NCH ((N_NODES + 255) / 256)   // 196 scan chunks

struct Args {
  const float* x; const int* ei; const float* ew;
  const float* W1; const float* b1;
  const float* W2; const float* b2;
  const float* W3; const float* b3;
  float* out;
  float* Yall;                         // [N][768] = all six y_k per layer
  float* A; float* B; float* C; float* D;
  int* ptrA; int* pos; int* srcs; float* wsrt;
  int* row32; int* col32; float* deg; float* dis; int* cnt; int* part;
  int* bar;                            // global barrier counter (host-zeroed)
};

// ---- lean grid barrier: 1 atomicAdd + 1 sleeping poller per block ----
__device__ __forceinline__ void gbar(int* bar, int target) {
  __threadfence();                      // release
  __syncthreads();
  if (threadIdx.x == 0) {
    atomicAdd(bar, 1);
    while (__hip_atomic_load(bar, __ATOMIC_ACQUIRE, __HIP_MEMORY_SCOPE_AGENT) < target)
      __builtin_amdgcn_s_sleep(8);
  }
  __syncthreads();
  __threadfence();                      // acquire
}

// ---- GEMM tile: out[n0:+64, c0:+64] = X @ B (+bias if addb) ----
// BMODE 0: B[k,c]=W[k*128+c] (tile covers 64 of 128 cols; 2 tiles/node-row)
// BMODE 1: B[k,c]=W3[(c/10)*K*10+k*10+c%10], c<60, one 64-col tile; ostride 64
template <int K_DIM, int BMODE>
__device__ __forceinline__ void gemm_tile(const float* __restrict__ X, const float* __restrict__ W,
                                          const float* __restrict__ bias, bool addb,
                                          float* __restrict__ outp, int ostride, int tile,
                                          float (&xt)[32][68], float (&bt)[32][64]) {
  const int tid = threadIdx.x;
  const int tx = tid & 15;
  const int ty = tid >> 4;
  int n0, c0;
  if (BMODE == 0) { n0 = (tile >> 1) * 64; c0 = (tile & 1) * 64; }
  else            { n0 = tile * 64;        c0 = 0; }
  float acc[4][4];
#pragma unroll
  for (int i = 0; i < 4; ++i)
#pragma unroll
    for (int j = 0; j < 4; ++j) acc[i][j] = 0.f;

  for (int k0 = 0; k0 < K_DIM; k0 += 32) {
#pragma unroll
    for (int i = 0; i < 8; ++i) {
      int idx = tid + i * 256;
      int nl = idx >> 5, kl = idx & 31;
      int nn = n0 + nl, kg = k0 + kl;
      float v = 0.f;
      if (nn < N_NODES && kg < K_DIM) v = X[(size_t)nn * K_DIM + kg];
      xt[kl][nl] = v;
    }
#pragma unroll
    for (int i = 0; i < 8; ++i) {
      int idx = tid + i * 256;
      int kl = idx >> 6, cl = idx & 63;
      int kg = k0 + kl;
      float v = 0.f;
      if (BMODE == 0) {
        if (kg < K_DIM) v = W[(size_t)kg * 128 + c0 + cl];
      } else {
        if (kg < K_DIM && cl < 6 * CDIM)
          v = W[(size_t)(cl / CDIM) * (K_DIM * CDIM) + (size_t)kg * CDIM + (cl % CDIM)];
      }
      bt[kl][cl] = v;
    }
    __syncthreads();
#pragma unroll
    for (int kk = 0; kk < 32; ++kk) {
      float4 xv = *(const float4*)&xt[kk][tx * 4];
      float4 bv = *(const float4*)&bt[kk][ty * 4];
      acc[0][0] += xv.x * bv.x; acc[0][1] += xv.x * bv.y; acc[0][2] += xv.x * bv.z; acc[0][3] += xv.x * bv.w;
      acc[1][0] += xv.y * bv.x; acc[1][1] += xv.y * bv.y; acc[1][2] += xv.y * bv.z; acc[1][3] += xv.y * bv.w;
      acc[2][0] += xv.z * bv.x; acc[2][1] += xv.z * bv.y; acc[2][2] += xv.z * bv.z; acc[2][3] += xv.z * bv.w;
      acc[3][0] += xv.w * bv.x; acc[3][1] += xv.w * bv.y; acc[3][2] += xv.w * bv.z; acc[3][3] += xv.w * bv.w;
    }
    __syncthreads();
  }
#pragma unroll
  for (int i = 0; i < 4; ++i) {
    int nn = n0 + tx * 4 + i;
    if (nn >= N_NODES) continue;
#pragma unroll
    for (int j = 0; j < 4; ++j) {
      int c = c0 + ty * 4 + j;
      float r = acc[i][j];
      if (addb) {
        if (BMODE == 0) r += bias[c];
        else if (c < CDIM) r += bias[c];
      }
      outp[(size_t)nn * ostride + c] = r;
    }
  }
}

// ---- hop d=128: Q[n] = maybeELU( Y[n] + sum_j w_j * P[src_j] ); strides in float4 units ----
template <bool ELU>
__device__ __forceinline__ void hop128_phase(const float4* __restrict__ P4, int pstr,
                                             const float4* __restrict__ Y4, int ystr,
                                             const int* __restrict__ ptr, const int* __restrict__ srcs,
                                             const float* __restrict__ w, float4* __restrict__ Q4) {
  const int lane = threadIdx.x & 63;
  const int wid = threadIdx.x >> 6;
  const int half = lane >> 5;
  const int f4 = lane & 31;
  for (int node = blockIdx.x * 4 + wid; node < N_NODES; node += gridDim.x * 4) {
    const int b = ptr[node], e = ptr[node + 1];
    const int len = e - b;
    const int c0 = (len + 1) >> 1;
    const int js = half ? (b + c0) : b;
    const int je = half ? e : (b + c0);
    float4 acc;
    if (half == 0) acc = Y4[(size_t)node * ystr + f4];
    else           acc = make_float4(0.f, 0.f, 0.f, 0.f);
    int j = js;
    for (; j + 3 < je; j += 4) {
      int s0 = srcs[j], s1 = srcs[j + 1], s2 = srcs[j + 2], s3 = srcs[j + 3];
      float w0 = w[j], w1 = w[j + 1], w2 = w[j + 2], w3 = w[j + 3];
      float4 v0 = P4[(size_t)s0 * pstr + f4];
      float4 v1 = P4[(size_t)s1 * pstr + f4];
      float4 v2 = P4[(size_t)s2 * pstr + f4];
      float4 v3 = P4[(size_t)s3 * pstr + f4];
      acc.x += w0 * v0.x + w1 * v1.x + w2 * v2.x + w3 * v3.x;
      acc.y += w0 * v0.y + w1 * v1.y + w2 * v2.y + w3 * v3.y;
      acc.z += w0 * v0.z + w1 * v1.z + w2 * v2.z + w3 * v3.z;
      acc.w += w0 * v0.w + w1 * v1.w + w2 * v2.w + w3 * v3.w;
    }
    for (; j < je; ++j) {
      float w0 = w[j];
      float4 v0 = P4[(size_t)srcs[j] * pstr + f4];
      acc.x += w0 * v0.x; acc.y += w0 * v0.y; acc.z += w0 * v0.z; acc.w += w0 * v0.w;
    }
    acc.x += __shfl_xor(acc.x, 32);
    acc.y += __shfl_xor(acc.y, 32);
    acc.z += __shfl_xor(acc.z, 32);
    acc.w += __shfl_xor(acc.w, 32);
    if (half == 0) {
      if (ELU) {
        acc.x = acc.x > 0.f ? acc.x : expm1f(acc.x);
        acc.y = acc.y > 0.f ? acc.y : expm1f(acc.y);
        acc.z = acc.z > 0.f ? acc.z : expm1f(acc.z);
        acc.w = acc.w > 0.f ? acc.w : expm1f(acc.w);
      }
      Q4[(size_t)node * 32 + f4] = acc;
    }
  }
}

// ---- hop d=10: out[n][f] = ybuf[n*64+yOff+f] + sum w*z[s*zStride+zOff+f] ----
__device__ __forceinline__ void hop10_phase(const float* __restrict__ z, int zStride, int zOff,
                                            const float* __restrict__ ybuf, int yOff,
                                            const int* __restrict__ ptr, const int* __restrict__ srcs,
                                            const float* __restrict__ wsrt, float* __restrict__ outp) {
  const int lane = threadIdx.x & 63;
  const int wid = threadIdx.x >> 6;
  const int sub = lane >> 4;
  const int f = lane & 15;
  for (int node = blockIdx.x * 4 + wid; node < N_NODES; node += gridDim.x * 4) {
    const int b = ptr[node], e = ptr[node + 1];
    const int len = e - b;
    const int js = b + (len * sub) / 4;
    const int je = b + (len * (sub + 1)) / 4;
    float acc = 0.f;
    if (f < CDIM) {
      if (sub == 0) acc = ybuf[(size_t)node * 64 + yOff + f];
      int j = js;
      for (; j + 1 < je; j += 2) {
        int s0 = srcs[j], s1 = srcs[j + 1];
        float w0 = wsrt[j], w1 = wsrt[j + 1];
        acc += w0 * z[(size_t)s0 * zStride + zOff + f] + w1 * z[(size_t)s1 * zStride + zOff + f];
      }
      if (j < je) acc += wsrt[j] * z[(size_t)srcs[j] * zStride + zOff + f];
    }
    acc += __shfl_xor(acc, 16);
    acc += __shfl_xor(acc, 32);
    if (sub == 0 && f < CDIM) outp[(size_t)node * CDIM + f] = acc;
  }
}

// ================= persistent kernel =================
__global__ __launch_bounds__(256, 4) void mega_kernel(Args a) {
  __shared__ float xt[32][68];
  __shared__ float bt[32][64];
  __shared__ int sdi[256];
  const int tid = threadIdx.x;
  const int gtid = blockIdx.x * blockDim.x + tid;
  const int gstride = gridDim.x * blockDim.x;
  const int gdim = gridDim.x;
  const int TG0 = ((N_NODES + 63) / 64) * 2;   // 1564 tiles per 128-col GEMM
  const int TG1 = (N_NODES + 63) / 64;         // 782
  int nb = 0;

  // P(-1): clock calibration — 300K dependent FMAs ≈ 1.2M cyc ≈ 0.5 ms @ 2.4 GHz
  {
    float ca = 1.0f + (float)(tid & 7) * 0.125f;
#pragma clang loop unroll(disable)
    for (int i = 0; i < 300000; ++i) ca = __builtin_fmaf(ca, 0.99999988f, 1.1920929e-7f);
    if (ca == 333.333f) a.out[tid & 7] = ca;   // keep-alive; out fully overwritten later
  }

  // P0: zero deg/cnt
  for (int i = gtid; i < N_NODES; i += gstride) { a.deg[i] = 0.f; a.cnt[i] = 0; }
  gbar(a.bar, (++nb) * gdim);

  // P1: convert edges + degree atomics
  {
    bool is64 = true;
    for (int i = 0; i < 32; ++i) if (a.ei[2 * i + 1] != 0) is64 = false;
    for (int e = gtid; e < N_EDGES; e += gstride) {
      int r, c;
      if (is64) { r = a.ei[2 * e]; c = a.ei[2 * (N_EDGES + e)]; }
      else      { r = a.ei[e];     c = a.ei[N_EDGES + e]; }
      a.row32[e] = r; a.col32[e] = c;
      atomicAdd(&a.deg[c], a.ew[e]);
      atomicAdd(&a.cnt[c], 1);
    }
  }
  gbar(a.bar, (++nb) * gdim);

  // P2: dis + per-chunk count sums
  for (int i = gtid; i < N_NODES; i += gstride) {
    float d = a.deg[i];
    a.dis[i] = d > 0.f ? rsqrtf(fmaxf(d, 1e-12f)) : 0.f;
  }
  for (int c = blockIdx.x; c < NCH; c += gdim) {
    int i = c * 256 + tid;
    sdi[tid] = (i < N_NODES) ? a.cnt[i] : 0;
    __syncthreads();
    for (int s = 128; s > 0; s >>= 1) { if (tid < s) sdi[tid] += sdi[tid + s]; __syncthreads(); }
    if (tid == 0) a.part[c] = sdi[0];
    __syncthreads();
  }
  gbar(a.bar, (++nb) * gdim);

  // P3: block 0 scans the 196 partials
  if (blockIdx.x == 0) {
    int v = (tid < NCH) ? a.part[tid] : 0;
    sdi[tid] = v;
    __syncthreads();
    for (int o = 1; o < 256; o <<= 1) {
      int t2 = (tid >= o) ? sdi[tid - o] : 0;
      __syncthreads();
      sdi[tid] += t2;
      __syncthreads();
    }
    if (tid < NCH) a.part[tid] = sdi[tid] - v;
    if (tid == 255) a.ptrA[N_NODES] = sdi[255];
  }
  gbar(a.bar, (++nb) * gdim);

  // P4: per-chunk exclusive scan -> ptrA, pos
  for (int c = blockIdx.x; c < NCH; c += gdim) {
    int i = c * 256 + tid;
    int v = (i < N_NODES) ? a.cnt[i] : 0;
    sdi[tid] = v;
    __syncthreads();
    for (int o = 1; o < 256; o <<= 1) {
      int t2 = (tid >= o) ? sdi[tid - o] : 0;
      __syncthreads();
      sdi[tid] += t2;
      __syncthreads();
    }
    if (i < N_NODES) { int p = a.part[c] + sdi[tid] - v; a.ptrA[i] = p; a.pos[i] = p; }
    __syncthreads();
  }
  gbar(a.bar, (++nb) * gdim);

  // P5: place into CSC + fused norm
  for (int e = gtid; e < N_EDGES; e += gstride) {
    int r = a.row32[e], c = a.col32[e];
    int slot = atomicAdd(&a.pos[c], 1);
    a.srcs[slot] = r;
    a.wsrt[slot] = a.dis[r] * a.ew[e] * a.dis[c];
  }
  gbar(a.bar, (++nb) * gdim);

  const float4* Y4 = (const float4*)a.Yall;    // stride 192 float4
  float4* A4 = (float4*)a.A; float4* B4 = (float4*)a.B;
  float4* C4 = (float4*)a.C; float4* D4 = (float4*)a.D;

  // ===== layer 1: all six y_k in one phase, then Horner hops =====
  for (int job = blockIdx.x; job < 6 * TG0; job += gdim) {
    int k = job / TG0, t = job % TG0;
    gemm_tile<F_IN_D, 0>(a.x, a.W1 + (size_t)k * F_IN_D * 128, a.b1, k == 0,
                         a.Yall + k * 128, 768, t, xt, bt);
  }
  gbar(a.bar, (++nb) * gdim);
  hop128_phase<false>(Y4 + 5 * 32, 192, Y4 + 4 * 32, 192, a.ptrA, a.srcs, a.wsrt, A4);
  gbar(a.bar, (++nb) * gdim);
  hop128_phase<false>(A4, 32, Y4 + 3 * 32, 192, a.ptrA, a.srcs, a.wsrt, B4);
  gbar(a.bar, (++nb) * gdim);
  hop128_phase<false>(B4, 32, Y4 + 2 * 32, 192, a.ptrA, a.srcs, a.wsrt, A4);
  gbar(a.bar, (++nb) * gdim);
  hop128_phase<false>(A4, 32, Y4 + 1 * 32, 192, a.ptrA, a.srcs, a.wsrt, B4);
  gbar(a.bar, (++nb) * gdim);
  hop128_phase<true>(B4, 32, Y4 + 0 * 32, 192, a.ptrA, a.srcs, a.wsrt, C4);
  gbar(a.bar, (++nb) * gdim);
  // h1 = C

  // ===== layer 2: in = C =====
  for (int job = blockIdx.x; job < 6 * TG0; job += gdim) {
    int k = job / TG0, t = job % TG0;
    gemm_tile<HDIM, 0>(a.C, a.W2 + (size_t)k * HDIM * 128, a.b2, k == 0,
                       a.Yall + k * 128, 768, t, xt, bt);
  }
  gbar(a.bar, (++nb) * gdim);
  hop128_phase<false>(Y4 + 5 * 32, 192, Y4 + 4 * 32, 192, a.ptrA, a.srcs, a.wsrt, A4);
  gbar(a.bar, (++nb) * gdim);
  hop128_phase<false>(A4, 32, Y4 + 3 * 32, 192, a.ptrA, a.srcs, a.wsrt, B4);
  gbar(a.bar, (++nb) * gdim);
  hop128_phase<false>(B4, 32, Y4 + 2 * 32, 192, a.ptrA, a.srcs, a.wsrt, A4);
  gbar(a.bar, (++nb) * gdim);
  hop128_phase<false>(A4, 32, Y4 + 1 * 32, 192, a.ptrA, a.srcs, a.wsrt, B4);
  gbar(a.bar, (++nb) * gdim);
  hop128_phase<true>(B4, 32, Y4 + 0 * 32, 192, a.ptrA, a.srcs, a.wsrt, D4);
  gbar(a.bar, (++nb) * gdim);
  // h2 = D

  // ===== layer 3: in = D; ybuf = A [N][64]; z ping-pong in B, C =====
  for (int t = blockIdx.x; t < TG1; t += gdim)
    gemm_tile<HDIM, 1>(a.D, a.W3, a.b3, true, a.A, 64, t, xt, bt);
  gbar(a.bar, (++nb) * gdim);
  hop10_phase(a.A, 64, 50, a.A, 40, a.ptrA, a.srcs, a.wsrt, a.B); gbar(a.bar, (++nb) * gdim);
  hop10_phase(a.B, 10, 0, a.A, 30, a.ptrA, a.srcs, a.wsrt, a.C); gbar(a.bar, (++nb) * gdim);
  hop10_phase(a.C, 10, 0, a.A, 20, a.ptrA, a.srcs, a.wsrt, a.B); gbar(a.bar, (++nb) * gdim);
  hop10_phase(a.B, 10, 0, a.A, 10, a.ptrA, a.srcs, a.wsrt, a.C); gbar(a.bar, (++nb) * gdim);
  hop10_phase(a.C, 10, 0, a.A, 0, a.ptrA, a.srcs, a.wsrt, a.out);
}

// ---------------- host ----------------

extern "C" void kernel_launch(void* const* d_in, const int* in_sizes, int n_in,
                              void* d_out, int out_size, void* d_ws, size_t ws_size,
                              hipStream_t stream) {
  Args a;
  a.x  = (const float*)d_in[0];
  a.ei = (const int*)d_in[1];
  a.ew = (const float*)d_in[2];
  a.W1 = (const float*)d_in[3];
  a.b1 = (const float*)d_in[4];
  a.W2 = (const float*)d_in[5];
  a.b2 = (const float*)d_in[6];
  a.W3 = (const float*)d_in[7];
  a.b3 = (const float*)d_in[8];
  a.out = (float*)d_out;

  const int N = N_NODES, E = N_EDGES;
  char* base = (char*)d_ws;
  size_t off = 0;
  auto alloc = [&](size_t bytes) -> char* {
    char* p = base + off;
    off += (bytes + 255) & ~(size_t)255;
    return p;
  };
  a.Yall = (float*)alloc((size_t)N * 768 * 4);   // 153.6 MB
  a.A = (float*)alloc((size_t)N * 128 * 4);
  a.B = (float*)alloc((size_t)N * 128 * 4);
  a.C = (float*)alloc((size_t)N * 128 * 4);
  a.D = (float*)alloc((size_t)N * 128 * 4);
  a.ptrA = (int*)alloc((size_t)(N + 1) * 4);
  a.pos  = (int*)alloc((size_t)N * 4);
  a.srcs = (int*)alloc((size_t)E * 4);
  a.wsrt = (float*)alloc((size_t)E * 4);
  a.bar  = (int*)alloc(256 * 4);

  // prep transients overlay Yall (first written in layer-1 GEMM phase, after prep)
  char* t = (char*)a.Yall;
  a.row32 = (int*)t;            t += (size_t)E * 4;
  a.col32 = (int*)t;            t += (size_t)E * 4;
  a.deg   = (float*)t;          t += (size_t)N * 4;
  a.dis   = (float*)t;          t += (size_t)N * 4;
  a.cnt   = (int*)t;            t += (size_t)N * 4;
  a.part  = (int*)t;            t += 2048 * 4;

  hipMemsetAsync(a.bar, 0, 256 * 4, stream);     // barrier counter must start at 0 each call

  int occ = 0;
  hipOccupancyMaxActiveBlocksPerMultiprocessor(&occ, (const void*)mega_kernel, 256, 0);
  int grid = occ * 256;
  if (grid > 1024) grid = 1024;
  if (grid < 64) grid = 64;

  void* args[] = { &a };
  hipLaunchCooperativeKernel((const void*)mega_kernel, dim3(grid), dim3(256), args, 0, stream);

  (void)in_sizes; (void)n_in; (void)out_size; (void)ws_size;
}

// Round 12
// 6249.898 us; speedup vs baseline: 2.5441x; 1.7996x over previous
//
#include <hip/hip_runtime.h>
#include <cstdint>
#include <cstddef>

#define N_NODES 50000
#define N_EDGES 800000
#define F_IN_D 100
#define HDIM 128
#define CDIM 10
#define NCH ((N_NODES + 255) / 256)   // 196 scan chunks

struct Args {
  const float* x; const int* ei; const float* ew;
  const float* W1; const float* b1;
  const float* W2; const float* b2;
  const float* W3; const float* b3;
  float* out;
  float* Yall;                         // [N][768] = all six y_k of current layer
  float* A; float* B; float* C; float* D;
  int* ptrA; int* pos; int* srcs; float* wsrt;
  int* row32; int* col32; float* deg; float* dis; int* cnt; int* part;
  int* bar;                            // global barrier counter (host-zeroed)
};

// ---- grid barrier (R10-proven implementation; do not modify) ----
__device__ __forceinline__ void gbar(int* bar, int target) {
  __threadfence();                      // release
  __syncthreads();
  if (threadIdx.x == 0) {
    atomicAdd(bar, 1);
    while (__hip_atomic_load(bar, __ATOMIC_ACQUIRE, __HIP_MEMORY_SCOPE_AGENT) < target)
      __builtin_amdgcn_s_sleep(8);
  }
  __syncthreads();
  __threadfence();                      // acquire
}

// ---- GEMM tile: out[n0:+64, c0:+64] = X @ B (+bias if addb) ----
// BMODE 0: B[k,c]=W[k*128+c] (2 tiles/node-row). BMODE 1: W3 concat layout, 64-col tile.
template <int K_DIM, int BMODE>
__device__ __forceinline__ void gemm_tile(const float* __restrict__ X, const float* __restrict__ W,
                                          const float* __restrict__ bias, bool addb,
                                          float* __restrict__ outp, int ostride, int tile,
                                          float (&xt)[32][68], float (&bt)[32][64]) {
  const int tid = threadIdx.x;
  const int tx = tid & 15;
  const int ty = tid >> 4;
  int n0, c0;
  if (BMODE == 0) { n0 = (tile >> 1) * 64; c0 = (tile & 1) * 64; }
  else            { n0 = tile * 64;        c0 = 0; }
  float acc[4][4];
#pragma unroll
  for (int i = 0; i < 4; ++i)
#pragma unroll
    for (int j = 0; j < 4; ++j) acc[i][j] = 0.f;

  for (int k0 = 0; k0 < K_DIM; k0 += 32) {
#pragma unroll
    for (int i = 0; i < 8; ++i) {
      int idx = tid + i * 256;
      int nl = idx >> 5, kl = idx & 31;
      int nn = n0 + nl, kg = k0 + kl;
      float v = 0.f;
      if (nn < N_NODES && kg < K_DIM) v = X[(size_t)nn * K_DIM + kg];
      xt[kl][nl] = v;
    }
#pragma unroll
    for (int i = 0; i < 8; ++i) {
      int idx = tid + i * 256;
      int kl = idx >> 6, cl = idx & 63;
      int kg = k0 + kl;
      float v = 0.f;
      if (BMODE == 0) {
        if (kg < K_DIM) v = W[(size_t)kg * 128 + c0 + cl];
      } else {
        if (kg < K_DIM && cl < 6 * CDIM)
          v = W[(size_t)(cl / CDIM) * (K_DIM * CDIM) + (size_t)kg * CDIM + (cl % CDIM)];
      }
      bt[kl][cl] = v;
    }
    __syncthreads();
#pragma unroll
    for (int kk = 0; kk < 32; ++kk) {
      float4 xv = *(const float4*)&xt[kk][tx * 4];
      float4 bv = *(const float4*)&bt[kk][ty * 4];
      acc[0][0] += xv.x * bv.x; acc[0][1] += xv.x * bv.y; acc[0][2] += xv.x * bv.z; acc[0][3] += xv.x * bv.w;
      acc[1][0] += xv.y * bv.x; acc[1][1] += xv.y * bv.y; acc[1][2] += xv.y * bv.z; acc[1][3] += xv.y * bv.w;
      acc[2][0] += xv.z * bv.x; acc[2][1] += xv.z * bv.y; acc[2][2] += xv.z * bv.z; acc[2][3] += xv.z * bv.w;
      acc[3][0] += xv.w * bv.x; acc[3][1] += xv.w * bv.y; acc[3][2] += xv.w * bv.z; acc[3][3] += xv.w * bv.w;
    }
    __syncthreads();
  }
#pragma unroll
  for (int i = 0; i < 4; ++i) {
    int nn = n0 + tx * 4 + i;
    if (nn >= N_NODES) continue;
#pragma unroll
    for (int j = 0; j < 4; ++j) {
      int c = c0 + ty * 4 + j;
      float r = acc[i][j];
      if (addb) {
        if (BMODE == 0) r += bias[c];
        else if (c < CDIM) r += bias[c];
      }
      outp[(size_t)nn * ostride + c] = r;
    }
  }
}

// ---- hop d=128: Q[n] = maybeELU( Y[n] + sum_j w_j * P[src_j] ); strides in float4 units ----
template <bool ELU>
__device__ __forceinline__ void hop128_phase(const float4* __restrict__ P4, int pstr,
                                             const float4* __restrict__ Y4, int ystr,
                                             const int* __restrict__ ptr, const int* __restrict__ srcs,
                                             const float* __restrict__ w, float4* __restrict__ Q4) {
  const int lane = threadIdx.x & 63;
  const int wid = threadIdx.x >> 6;
  const int half = lane >> 5;
  const int f4 = lane & 31;
  for (int node = blockIdx.x * 4 + wid; node < N_NODES; node += gridDim.x * 4) {
    const int b = ptr[node], e = ptr[node + 1];
    const int len = e - b;
    const int c0 = (len + 1) >> 1;
    const int js = half ? (b + c0) : b;
    const int je = half ? e : (b + c0);
    float4 acc;
    if (half == 0) acc = Y4[(size_t)node * ystr + f4];
    else           acc = make_float4(0.f, 0.f, 0.f, 0.f);
    int j = js;
    for (; j + 3 < je; j += 4) {
      int s0 = srcs[j], s1 = srcs[j + 1], s2 = srcs[j + 2], s3 = srcs[j + 3];
      float w0 = w[j], w1 = w[j + 1], w2 = w[j + 2], w3 = w[j + 3];
      float4 v0 = P4[(size_t)s0 * pstr + f4];
      float4 v1 = P4[(size_t)s1 * pstr + f4];
      float4 v2 = P4[(size_t)s2 * pstr + f4];
      float4 v3 = P4[(size_t)s3 * pstr + f4];
      acc.x += w0 * v0.x + w1 * v1.x + w2 * v2.x + w3 * v3.x;
      acc.y += w0 * v0.y + w1 * v1.y + w2 * v2.y + w3 * v3.y;
      acc.z += w0 * v0.z + w1 * v1.z + w2 * v2.z + w3 * v3.z;
      acc.w += w0 * v0.w + w1 * v1.w + w2 * v2.w + w3 * v3.w;
    }
    for (; j < je; ++j) {
      float w0 = w[j];
      float4 v0 = P4[(size_t)srcs[j] * pstr + f4];
      acc.x += w0 * v0.x; acc.y += w0 * v0.y; acc.z += w0 * v0.z; acc.w += w0 * v0.w;
    }
    acc.x += __shfl_xor(acc.x, 32);
    acc.y += __shfl_xor(acc.y, 32);
    acc.z += __shfl_xor(acc.z, 32);
    acc.w += __shfl_xor(acc.w, 32);
    if (half == 0) {
      if (ELU) {
        acc.x = acc.x > 0.f ? acc.x : expm1f(acc.x);
        acc.y = acc.y > 0.f ? acc.y : expm1f(acc.y);
        acc.z = acc.z > 0.f ? acc.z : expm1f(acc.z);
        acc.w = acc.w > 0.f ? acc.w : expm1f(acc.w);
      }
      Q4[(size_t)node * 32 + f4] = acc;
    }
  }
}

// ---- hop d=10 ----
__device__ __forceinline__ void hop10_phase(const float* __restrict__ z, int zStride, int zOff,
                                            const float* __restrict__ ybuf, int yOff,
                                            const int* __restrict__ ptr, const int* __restrict__ srcs,
                                            const float* __restrict__ wsrt, float* __restrict__ outp) {
  const int lane = threadIdx.x & 63;
  const int wid = threadIdx.x >> 6;
  const int sub = lane >> 4;
  const int f = lane & 15;
  for (int node = blockIdx.x * 4 + wid; node < N_NODES; node += gridDim.x * 4) {
    const int b = ptr[node], e = ptr[node + 1];
    const int len = e - b;
    const int js = b + (len * sub) / 4;
    const int je = b + (len * (sub + 1)) / 4;
    float acc = 0.f;
    if (f < CDIM) {
      if (sub == 0) acc = ybuf[(size_t)node * 64 + yOff + f];
      int j = js;
      for (; j + 1 < je; j += 2) {
        int s0 = srcs[j], s1 = srcs[j + 1];
        float w0 = wsrt[j], w1 = wsrt[j + 1];
        acc += w0 * z[(size_t)s0 * zStride + zOff + f] + w1 * z[(size_t)s1 * zStride + zOff + f];
      }
      if (j < je) acc += wsrt[j] * z[(size_t)srcs[j] * zStride + zOff + f];
    }
    acc += __shfl_xor(acc, 16);
    acc += __shfl_xor(acc, 32);
    if (sub == 0 && f < CDIM) outp[(size_t)node * CDIM + f] = acc;
  }
}

// ================= persistent kernel, 21 barriers =================
__global__ __launch_bounds__(256, 4) void mega_kernel(Args a) {
  __shared__ float xt[32][68];
  __shared__ float bt[32][64];
  __shared__ int sdi[256];
  const int tid = threadIdx.x;
  const int gtid = blockIdx.x * blockDim.x + tid;
  const int gstride = gridDim.x * blockDim.x;
  const int gdim = gridDim.x;
  const int TG0 = ((N_NODES + 63) / 64) * 2;   // 1564 tiles per 128-col GEMM
  const int TG1 = (N_NODES + 63) / 64;         // 782
  int nb = 0;

  // P1: convert edges + degree atomics, then layer-1 GEMM (independent of prep)
  {
    bool is64 = true;
    for (int i = 0; i < 32; ++i) if (a.ei[2 * i + 1] != 0) is64 = false;
    for (int e = gtid; e < N_EDGES; e += gstride) {
      int r, c;
      if (is64) { r = a.ei[2 * e]; c = a.ei[2 * (N_EDGES + e)]; }
      else      { r = a.ei[e];     c = a.ei[N_EDGES + e]; }
      a.row32[e] = r; a.col32[e] = c;
      atomicAdd(&a.deg[c], a.ew[e]);
      atomicAdd(&a.cnt[c], 1);
    }
  }
  for (int job = blockIdx.x; job < 6 * TG0; job += gdim) {
    int k = job / TG0, t = job % TG0;
    gemm_tile<F_IN_D, 0>(a.x, a.W1 + (size_t)k * F_IN_D * 128, a.b1, k == 0,
                         a.Yall + k * 128, 768, t, xt, bt);
  }
  gbar(a.bar, (++nb) * gdim);

  // P2: dis + per-chunk count sums
  for (int i = gtid; i < N_NODES; i += gstride) {
    float d = a.deg[i];
    a.dis[i] = d > 0.f ? rsqrtf(fmaxf(d, 1e-12f)) : 0.f;
  }
  for (int c = blockIdx.x; c < NCH; c += gdim) {
    int i = c * 256 + tid;
    sdi[tid] = (i < N_NODES) ? a.cnt[i] : 0;
    __syncthreads();
    for (int s = 128; s > 0; s >>= 1) { if (tid < s) sdi[tid] += sdi[tid + s]; __syncthreads(); }
    if (tid == 0) a.part[c] = sdi[0];
    __syncthreads();
  }
  gbar(a.bar, (++nb) * gdim);

  // P3: block 0 scans the 196 partials
  if (blockIdx.x == 0) {
    int v = (tid < NCH) ? a.part[tid] : 0;
    sdi[tid] = v;
    __syncthreads();
    for (int o = 1; o < 256; o <<= 1) {
      int t2 = (tid >= o) ? sdi[tid - o] : 0;
      __syncthreads();
      sdi[tid] += t2;
      __syncthreads();
    }
    if (tid < NCH) a.part[tid] = sdi[tid] - v;
    if (tid == 255) a.ptrA[N_NODES] = sdi[255];
  }
  gbar(a.bar, (++nb) * gdim);

  // P4: per-chunk exclusive scan -> ptrA, pos
  for (int c = blockIdx.x; c < NCH; c += gdim) {
    int i = c * 256 + tid;
    int v = (i < N_NODES) ? a.cnt[i] : 0;
    sdi[tid] = v;
    __syncthreads();
    for (int o = 1; o < 256; o <<= 1) {
      int t2 = (tid >= o) ? sdi[tid - o] : 0;
      __syncthreads();
      sdi[tid] += t2;
      __syncthreads();
    }
    if (i < N_NODES) { int p = a.part[c] + sdi[tid] - v; a.ptrA[i] = p; a.pos[i] = p; }
    __syncthreads();
  }
  gbar(a.bar, (++nb) * gdim);

  // P5: place into CSC + fused norm
  for (int e = gtid; e < N_EDGES; e += gstride) {
    int r = a.row32[e], c = a.col32[e];
    int slot = atomicAdd(&a.pos[c], 1);
    a.srcs[slot] = r;
    a.wsrt[slot] = a.dis[r] * a.ew[e] * a.dis[c];
  }
  gbar(a.bar, (++nb) * gdim);

  const float4* Y4 = (const float4*)a.Yall;    // row stride 192 float4
  float4* A4 = (float4*)a.A; float4* B4 = (float4*)a.B;
  float4* C4 = (float4*)a.C; float4* D4 = (float4*)a.D;

  // ===== layer 1 hops (y_k already in Yall) =====
  hop128_phase<false>(Y4 + 5 * 32, 192, Y4 + 4 * 32, 192, a.ptrA, a.srcs, a.wsrt, A4);
  gbar(a.bar, (++nb) * gdim);
  hop128_phase<false>(A4, 32, Y4 + 3 * 32, 192, a.ptrA, a.srcs, a.wsrt, B4);
  gbar(a.bar, (++nb) * gdim);
  hop128_phase<false>(B4, 32, Y4 + 2 * 32, 192, a.ptrA, a.srcs, a.wsrt, A4);
  gbar(a.bar, (++nb) * gdim);
  hop128_phase<false>(A4, 32, Y4 + 1 * 32, 192, a.ptrA, a.srcs, a.wsrt, B4);
  gbar(a.bar, (++nb) * gdim);
  hop128_phase<true>(B4, 32, Y4 + 0 * 32, 192, a.ptrA, a.srcs, a.wsrt, C4);
  gbar(a.bar, (++nb) * gdim);
  // h1 = C

  // ===== layer 2: GEMM then hops =====
  for (int job = blockIdx.x; job < 6 * TG0; job += gdim) {
    int k = job / TG0, t = job % TG0;
    gemm_tile<HDIM, 0>(a.C, a.W2 + (size_t)k * HDIM * 128, a.b2, k == 0,
                       a.Yall + k * 128, 768, t, xt, bt);
  }
  gbar(a.bar, (++nb) * gdim);
  hop128_phase<false>(Y4 + 5 * 32, 192, Y4 + 4 * 32, 192, a.ptrA, a.srcs, a.wsrt, A4);
  gbar(a.bar, (++nb) * gdim);
  hop128_phase<false>(A4, 32, Y4 + 3 * 32, 192, a.ptrA, a.srcs, a.wsrt, B4);
  gbar(a.bar, (++nb) * gdim);
  hop128_phase<false>(B4, 32, Y4 + 2 * 32, 192, a.ptrA, a.srcs, a.wsrt, A4);
  gbar(a.bar, (++nb) * gdim);
  hop128_phase<false>(A4, 32, Y4 + 1 * 32, 192, a.ptrA, a.srcs, a.wsrt, B4);
  gbar(a.bar, (++nb) * gdim);
  hop128_phase<true>(B4, 32, Y4 + 0 * 32, 192, a.ptrA, a.srcs, a.wsrt, D4);
  gbar(a.bar, (++nb) * gdim);
  // h2 = D

  // ===== layer 3: GEMM (ybuf = A [N][64]) then hop10 chain (z ping-pong B, C) =====
  for (int t = blockIdx.x; t < TG1; t += gdim)
    gemm_tile<HDIM, 1>(a.D, a.W3, a.b3, true, a.A, 64, t, xt, bt);
  gbar(a.bar, (++nb) * gdim);
  hop10_phase(a.A, 64, 50, a.A, 40, a.ptrA, a.srcs, a.wsrt, a.B); gbar(a.bar, (++nb) * gdim);
  hop10_phase(a.B, 10, 0, a.A, 30, a.ptrA, a.srcs, a.wsrt, a.C); gbar(a.bar, (++nb) * gdim);
  hop10_phase(a.C, 10, 0, a.A, 20, a.ptrA, a.srcs, a.wsrt, a.B); gbar(a.bar, (++nb) * gdim);
  hop10_phase(a.B, 10, 0, a.A, 10, a.ptrA, a.srcs, a.wsrt, a.C); gbar(a.bar, (++nb) * gdim);
  hop10_phase(a.C, 10, 0, a.A, 0, a.ptrA, a.srcs, a.wsrt, a.out);
}

// ---------------- host ----------------

extern "C" void kernel_launch(void* const* d_in, const int* in_sizes, int n_in,
                              void* d_out, int out_size, void* d_ws, size_t ws_size,
                              hipStream_t stream) {
  Args a;
  a.x  = (const float*)d_in[0];
  a.ei = (const int*)d_in[1];
  a.ew = (const float*)d_in[2];
  a.W1 = (const float*)d_in[3];
  a.b1 = (const float*)d_in[4];
  a.W2 = (const float*)d_in[5];
  a.b2 = (const float*)d_in[6];
  a.W3 = (const float*)d_in[7];
  a.b3 = (const float*)d_in[8];
  a.out = (float*)d_out;

  const int N = N_NODES, E = N_EDGES;
  char* base = (char*)d_ws;
  size_t off = 0;
  auto alloc = [&](size_t bytes) -> char* {
    char* p = base + off;
    off += (bytes + 255) & ~(size_t)255;
    return p;
  };
  a.Yall = (float*)alloc((size_t)N * 768 * 4);   // 153.6 MB
  a.A = (float*)alloc((size_t)N * 128 * 4);
  a.B = (float*)alloc((size_t)N * 128 * 4);
  a.C = (float*)alloc((size_t)N * 128 * 4);
  a.D = (float*)alloc((size_t)N * 128 * 4);
  a.ptrA = (int*)alloc((size_t)(N + 1) * 4);
  a.pos  = (int*)alloc((size_t)N * 4);
  a.srcs = (int*)alloc((size_t)E * 4);
  a.wsrt = (float*)alloc((size_t)E * 4);
  a.bar  = (int*)alloc(256 * 4);

  // prep transients overlay A (A first written by the first layer-1 hop, after P5).
  // Yall must stay clear: layer-1 GEMM writes it during P1 (concurrent with prep).
  char* t = (char*)a.A;
  a.row32 = (int*)t;            t += (size_t)E * 4;
  a.col32 = (int*)t;            t += (size_t)E * 4;
  a.deg   = (float*)t;          t += (size_t)N * 4;
  a.dis   = (float*)t;          t += (size_t)N * 4;
  a.cnt   = (int*)t;            t += (size_t)N * 4;
  a.part  = (int*)t;            t += 2048 * 4;

  hipMemsetAsync(a.bar, 0, 256 * 4, stream);
  hipMemsetAsync(a.deg, 0, (size_t)N * 4, stream);
  hipMemsetAsync(a.cnt, 0, (size_t)N * 4, stream);

  int occ = 0;
  hipOccupancyMaxActiveBlocksPerMultiprocessor(&occ, (const void*)mega_kernel, 256, 0);
  int grid = occ * 256;
  if (grid > 1024) grid = 1024;
  if (grid < 64) grid = 64;

  void* args[] = { &a };
  hipLaunchCooperativeKernel((const void*)mega_kernel, dim3(grid), dim3(256), args, 0, stream);

  (void)in_sizes; (void)n_in; (void)out_size; (void)ws_size;
}

// Round 13
// 4974.449 us; speedup vs baseline: 3.1965x; 1.2564x over previous
//
#include <hip/hip_runtime.h>
#include <cstdint>
#include <cstddef>

#define N_NODES 50000
#define N_EDGES 800000
#define F_IN_D 100
#define HDIM 128
#define CDIM 10
#define NCH ((N_NODES + 255) / 256)   // 196 scan chunks

struct Args {
  const float* x; const int* ei; const float* ew;
  const float* W1; const float* b1;
  const float* W2; const float* b2;
  const float* W3; const float* b3;
  float* out;
  float* Yall;                         // [N][768] = all six y_k of current layer
  float* A; float* B; float* C; float* D;
  int* ptrA; int* pos; int* srcs; float* wsrt;
  int* row32; int* col32; float* deg; float* dis; int* cnt; int* part;
  int* bar;                            // global barrier counter (host-zeroed)
};

// ---- grid barrier v3: leader-only cache maintenance + ACQUIRE poll ----
// Block sits on ONE CU: leader's cache-wide writeback/invalidate covers the
// block's L1 and its XCD's L2. __syncthreads drains vmcnt, so all block
// stores are in L2 before the leader's release fence. Poll keeps ACQUIRE
// (R10-proven): a RELAXED poll can spin on stale L1 forever (R11 hang).
__device__ __forceinline__ void gbar(int* bar, int target) {
  __syncthreads();                     // all block stores issued & drained
  if (threadIdx.x == 0) {
    __threadfence();                   // release: writeback this XCD's L2 (cache-wide op)
    atomicAdd(bar, 1);                 // device-scope arrival
    while (__hip_atomic_load(bar, __ATOMIC_ACQUIRE, __HIP_MEMORY_SCOPE_AGENT) < target)
      __builtin_amdgcn_s_sleep(8);
    __threadfence();                   // acquire: invalidate L1/L2 for this CU/XCD
  }
  __syncthreads();                     // others blocked until leader sees all arrivals
}

// ---- GEMM tile: out[n0:+64, c0:+64] = X @ B (+bias if addb) ----
// BMODE 0: B[k,c]=W[k*128+c] (2 tiles/node-row). BMODE 1: W3 concat layout, 64-col tile.
template <int K_DIM, int BMODE>
__device__ __forceinline__ void gemm_tile(const float* __restrict__ X, const float* __restrict__ W,
                                          const float* __restrict__ bias, bool addb,
                                          float* __restrict__ outp, int ostride, int tile,
                                          float (&xt)[32][68], float (&bt)[32][64]) {
  const int tid = threadIdx.x;
  const int tx = tid & 15;
  const int ty = tid >> 4;
  int n0, c0;
  if (BMODE == 0) { n0 = (tile >> 1) * 64; c0 = (tile & 1) * 64; }
  else            { n0 = tile * 64;        c0 = 0; }
  float acc[4][4];
#pragma unroll
  for (int i = 0; i < 4; ++i)
#pragma unroll
    for (int j = 0; j < 4; ++j) acc[i][j] = 0.f;

  for (int k0 = 0; k0 < K_DIM; k0 += 32) {
#pragma unroll
    for (int i = 0; i < 8; ++i) {
      int idx = tid + i * 256;
      int nl = idx >> 5, kl = idx & 31;
      int nn = n0 + nl, kg = k0 + kl;
      float v = 0.f;
      if (nn < N_NODES && kg < K_DIM) v = X[(size_t)nn * K_DIM + kg];
      xt[kl][nl] = v;
    }
#pragma unroll
    for (int i = 0; i < 8; ++i) {
      int idx = tid + i * 256;
      int kl = idx >> 6, cl = idx & 63;
      int kg = k0 + kl;
      float v = 0.f;
      if (BMODE == 0) {
        if (kg < K_DIM) v = W[(size_t)kg * 128 + c0 + cl];
      } else {
        if (kg < K_DIM && cl < 6 * CDIM)
          v = W[(size_t)(cl / CDIM) * (K_DIM * CDIM) + (size_t)kg * CDIM + (cl % CDIM)];
      }
      bt[kl][cl] = v;
    }
    __syncthreads();
#pragma unroll
    for (int kk = 0; kk < 32; ++kk) {
      float4 xv = *(const float4*)&xt[kk][tx * 4];
      float4 bv = *(const float4*)&bt[kk][ty * 4];
      acc[0][0] += xv.x * bv.x; acc[0][1] += xv.x * bv.y; acc[0][2] += xv.x * bv.z; acc[0][3] += xv.x * bv.w;
      acc[1][0] += xv.y * bv.x; acc[1][1] += xv.y * bv.y; acc[1][2] += xv.y * bv.z; acc[1][3] += xv.y * bv.w;
      acc[2][0] += xv.z * bv.x; acc[2][1] += xv.z * bv.y; acc[2][2] += xv.z * bv.z; acc[2][3] += xv.z * bv.w;
      acc[3][0] += xv.w * bv.x; acc[3][1] += xv.w * bv.y; acc[3][2] += xv.w * bv.z; acc[3][3] += xv.w * bv.w;
    }
    __syncthreads();
  }
#pragma unroll
  for (int i = 0; i < 4; ++i) {
    int nn = n0 + tx * 4 + i;
    if (nn >= N_NODES) continue;
#pragma unroll
    for (int j = 0; j < 4; ++j) {
      int c = c0 + ty * 4 + j;
      float r = acc[i][j];
      if (addb) {
        if (BMODE == 0) r += bias[c];
        else if (c < CDIM) r += bias[c];
      }
      outp[(size_t)nn * ostride + c] = r;
    }
  }
}

// ---- hop d=128: Q[n] = maybeELU( Y[n] + sum_j w_j * P[src_j] ); strides in float4 units ----
template <bool ELU>
__device__ __forceinline__ void hop128_phase(const float4* __restrict__ P4, int pstr,
                                             const float4* __restrict__ Y4, int ystr,
                                             const int* __restrict__ ptr, const int* __restrict__ srcs,
                                             const float* __restrict__ w, float4* __restrict__ Q4) {
  const int lane = threadIdx.x & 63;
  const int wid = threadIdx.x >> 6;
  const int half = lane >> 5;
  const int f4 = lane & 31;
  for (int node = blockIdx.x * 4 + wid; node < N_NODES; node += gridDim.x * 4) {
    const int b = ptr[node], e = ptr[node + 1];
    const int len = e - b;
    const int c0 = (len + 1) >> 1;
    const int js = half ? (b + c0) : b;
    const int je = half ? e : (b + c0);
    float4 acc;
    if (half == 0) acc = Y4[(size_t)node * ystr + f4];
    else           acc = make_float4(0.f, 0.f, 0.f, 0.f);
    int j = js;
    for (; j + 3 < je; j += 4) {
      int s0 = srcs[j], s1 = srcs[j + 1], s2 = srcs[j + 2], s3 = srcs[j + 3];
      float w0 = w[j], w1 = w[j + 1], w2 = w[j + 2], w3 = w[j + 3];
      float4 v0 = P4[(size_t)s0 * pstr + f4];
      float4 v1 = P4[(size_t)s1 * pstr + f4];
      float4 v2 = P4[(size_t)s2 * pstr + f4];
      float4 v3 = P4[(size_t)s3 * pstr + f4];
      acc.x += w0 * v0.x + w1 * v1.x + w2 * v2.x + w3 * v3.x;
      acc.y += w0 * v0.y + w1 * v1.y + w2 * v2.y + w3 * v3.y;
      acc.z += w0 * v0.z + w1 * v1.z + w2 * v2.z + w3 * v3.z;
      acc.w += w0 * v0.w + w1 * v1.w + w2 * v2.w + w3 * v3.w;
    }
    for (; j < je; ++j) {
      float w0 = w[j];
      float4 v0 = P4[(size_t)srcs[j] * pstr + f4];
      acc.x += w0 * v0.x; acc.y += w0 * v0.y; acc.z += w0 * v0.z; acc.w += w0 * v0.w;
    }
    acc.x += __shfl_xor(acc.x, 32);
    acc.y += __shfl_xor(acc.y, 32);
    acc.z += __shfl_xor(acc.z, 32);
    acc.w += __shfl_xor(acc.w, 32);
    if (half == 0) {
      if (ELU) {
        acc.x = acc.x > 0.f ? acc.x : expm1f(acc.x);
        acc.y = acc.y > 0.f ? acc.y : expm1f(acc.y);
        acc.z = acc.z > 0.f ? acc.z : expm1f(acc.z);
        acc.w = acc.w > 0.f ? acc.w : expm1f(acc.w);
      }
      Q4[(size_t)node * 32 + f4] = acc;
    }
  }
}

// ---- hop d=10 ----
__device__ __forceinline__ void hop10_phase(const float* __restrict__ z, int zStride, int zOff,
                                            const float* __restrict__ ybuf, int yOff,
                                            const int* __restrict__ ptr, const int* __restrict__ srcs,
                                            const float* __restrict__ wsrt, float* __restrict__ outp) {
  const int lane = threadIdx.x & 63;
  const int wid = threadIdx.x >> 6;
  const int sub = lane >> 4;
  const int f = lane & 15;
  for (int node = blockIdx.x * 4 + wid; node < N_NODES; node += gridDim.x * 4) {
    const int b = ptr[node], e = ptr[node + 1];
    const int len = e - b;
    const int js = b + (len * sub) / 4;
    const int je = b + (len * (sub + 1)) / 4;
    float acc = 0.f;
    if (f < CDIM) {
      if (sub == 0) acc = ybuf[(size_t)node * 64 + yOff + f];
      int j = js;
      for (; j + 1 < je; j += 2) {
        int s0 = srcs[j], s1 = srcs[j + 1];
        float w0 = wsrt[j], w1 = wsrt[j + 1];
        acc += w0 * z[(size_t)s0 * zStride + zOff + f] + w1 * z[(size_t)s1 * zStride + zOff + f];
      }
      if (j < je) acc += wsrt[j] * z[(size_t)srcs[j] * zStride + zOff + f];
    }
    acc += __shfl_xor(acc, 16);
    acc += __shfl_xor(acc, 32);
    if (sub == 0 && f < CDIM) outp[(size_t)node * CDIM + f] = acc;
  }
}

// ================= persistent kernel, 21 barriers =================
__global__ __launch_bounds__(256, 4) void mega_kernel(Args a) {
  __shared__ float xt[32][68];
  __shared__ float bt[32][64];
  __shared__ int sdi[256];
  const int tid = threadIdx.x;
  const int gtid = blockIdx.x * blockDim.x + tid;
  const int gstride = gridDim.x * blockDim.x;
  const int gdim = gridDim.x;
  const int TG0 = ((N_NODES + 63) / 64) * 2;   // 1564 tiles per 128-col GEMM
  const int TG1 = (N_NODES + 63) / 64;         // 782
  int nb = 0;

  // P1: convert edges + degree atomics, then layer-1 GEMM (independent of prep)
  {
    bool is64 = true;
    for (int i = 0; i < 32; ++i) if (a.ei[2 * i + 1] != 0) is64 = false;
    for (int e = gtid; e < N_EDGES; e += gstride) {
      int r, c;
      if (is64) { r = a.ei[2 * e]; c = a.ei[2 * (N_EDGES + e)]; }
      else      { r = a.ei[e];     c = a.ei[N_EDGES + e]; }
      a.row32[e] = r; a.col32[e] = c;
      atomicAdd(&a.deg[c], a.ew[e]);
      atomicAdd(&a.cnt[c], 1);
    }
  }
  for (int job = blockIdx.x; job < 6 * TG0; job += gdim) {
    int k = job / TG0, t = job % TG0;
    gemm_tile<F_IN_D, 0>(a.x, a.W1 + (size_t)k * F_IN_D * 128, a.b1, k == 0,
                         a.Yall + k * 128, 768, t, xt, bt);
  }
  gbar(a.bar, (++nb) * gdim);

  // P2: dis + per-chunk count sums
  for (int i = gtid; i < N_NODES; i += gstride) {
    float d = a.deg[i];
    a.dis[i] = d > 0.f ? rsqrtf(fmaxf(d, 1e-12f)) : 0.f;
  }
  for (int c = blockIdx.x; c < NCH; c += gdim) {
    int i = c * 256 + tid;
    sdi[tid] = (i < N_NODES) ? a.cnt[i] : 0;
    __syncthreads();
    for (int s = 128; s > 0; s >>= 1) { if (tid < s) sdi[tid] += sdi[tid + s]; __syncthreads(); }
    if (tid == 0) a.part[c] = sdi[0];
    __syncthreads();
  }
  gbar(a.bar, (++nb) * gdim);

  // P3: block 0 scans the 196 partials
  if (blockIdx.x == 0) {
    int v = (tid < NCH) ? a.part[tid] : 0;
    sdi[tid] = v;
    __syncthreads();
    for (int o = 1; o < 256; o <<= 1) {
      int t2 = (tid >= o) ? sdi[tid - o] : 0;
      __syncthreads();
      sdi[tid] += t2;
      __syncthreads();
    }
    if (tid < NCH) a.part[tid] = sdi[tid] - v;
    if (tid == 255) a.ptrA[N_NODES] = sdi[255];
  }
  gbar(a.bar, (++nb) * gdim);

  // P4: per-chunk exclusive scan -> ptrA, pos
  for (int c = blockIdx.x; c < NCH; c += gdim) {
    int i = c * 256 + tid;
    int v = (i < N_NODES) ? a.cnt[i] : 0;
    sdi[tid] = v;
    __syncthreads();
    for (int o = 1; o < 256; o <<= 1) {
      int t2 = (tid >= o) ? sdi[tid - o] : 0;
      __syncthreads();
      sdi[tid] += t2;
      __syncthreads();
    }
    if (i < N_NODES) { int p = a.part[c] + sdi[tid] - v; a.ptrA[i] = p; a.pos[i] = p; }
    __syncthreads();
  }
  gbar(a.bar, (++nb) * gdim);

  // P5: place into CSC + fused norm
  for (int e = gtid; e < N_EDGES; e += gstride) {
    int r = a.row32[e], c = a.col32[e];
    int slot = atomicAdd(&a.pos[c], 1);
    a.srcs[slot] = r;
    a.wsrt[slot] = a.dis[r] * a.ew[e] * a.dis[c];
  }
  gbar(a.bar, (++nb) * gdim);

  const float4* Y4 = (const float4*)a.Yall;    // row stride 192 float4
  float4* A4 = (float4*)a.A; float4* B4 = (float4*)a.B;
  float4* C4 = (float4*)a.C; float4* D4 = (float4*)a.D;

  // ===== layer 1 hops (y_k already in Yall) =====
  hop128_phase<false>(Y4 + 5 * 32, 192, Y4 + 4 * 32, 192, a.ptrA, a.srcs, a.wsrt, A4);
  gbar(a.bar, (++nb) * gdim);
  hop128_phase<false>(A4, 32, Y4 + 3 * 32, 192, a.ptrA, a.srcs, a.wsrt, B4);
  gbar(a.bar, (++nb) * gdim);
  hop128_phase<false>(B4, 32, Y4 + 2 * 32, 192, a.ptrA, a.srcs, a.wsrt, A4);
  gbar(a.bar, (++nb) * gdim);
  hop128_phase<false>(A4, 32, Y4 + 1 * 32, 192, a.ptrA, a.srcs, a.wsrt, B4);
  gbar(a.bar, (++nb) * gdim);
  hop128_phase<true>(B4, 32, Y4 + 0 * 32, 192, a.ptrA, a.srcs, a.wsrt, C4);
  gbar(a.bar, (++nb) * gdim);
  // h1 = C

  // ===== layer 2: GEMM then hops =====
  for (int job = blockIdx.x; job < 6 * TG0; job += gdim) {
    int k = job / TG0, t = job % TG0;
    gemm_tile<HDIM, 0>(a.C, a.W2 + (size_t)k * HDIM * 128, a.b2, k == 0,
                       a.Yall + k * 128, 768, t, xt, bt);
  }
  gbar(a.bar, (++nb) * gdim);
  hop128_phase<false>(Y4 + 5 * 32, 192, Y4 + 4 * 32, 192, a.ptrA, a.srcs, a.wsrt, A4);
  gbar(a.bar, (++nb) * gdim);
  hop128_phase<false>(A4, 32, Y4 + 3 * 32, 192, a.ptrA, a.srcs, a.wsrt, B4);
  gbar(a.bar, (++nb) * gdim);
  hop128_phase<false>(B4, 32, Y4 + 2 * 32, 192, a.ptrA, a.srcs, a.wsrt, A4);
  gbar(a.bar, (++nb) * gdim);
  hop128_phase<false>(A4, 32, Y4 + 1 * 32, 192, a.ptrA, a.srcs, a.wsrt, B4);
  gbar(a.bar, (++nb) * gdim);
  hop128_phase<true>(B4, 32, Y4 + 0 * 32, 192, a.ptrA, a.srcs, a.wsrt, D4);
  gbar(a.bar, (++nb) * gdim);
  // h2 = D

  // ===== layer 3: GEMM (ybuf = A [N][64]) then hop10 chain (z ping-pong B, C) =====
  for (int t = blockIdx.x; t < TG1; t += gdim)
    gemm_tile<HDIM, 1>(a.D, a.W3, a.b3, true, a.A, 64, t, xt, bt);
  gbar(a.bar, (++nb) * gdim);
  hop10_phase(a.A, 64, 50, a.A, 40, a.ptrA, a.srcs, a.wsrt, a.B); gbar(a.bar, (++nb) * gdim);
  hop10_phase(a.B, 10, 0, a.A, 30, a.ptrA, a.srcs, a.wsrt, a.C); gbar(a.bar, (++nb) * gdim);
  hop10_phase(a.C, 10, 0, a.A, 20, a.ptrA, a.srcs, a.wsrt, a.B); gbar(a.bar, (++nb) * gdim);
  hop10_phase(a.B, 10, 0, a.A, 10, a.ptrA, a.srcs, a.wsrt, a.C); gbar(a.bar, (++nb) * gdim);
  hop10_phase(a.C, 10, 0, a.A, 0, a.ptrA, a.srcs, a.wsrt, a.out);
}

// ---------------- host ----------------

extern "C" void kernel_launch(void* const* d_in, const int* in_sizes, int n_in,
                              void* d_out, int out_size, void* d_ws, size_t ws_size,
                              hipStream_t stream) {
  Args a;
  a.x  = (const float*)d_in[0];
  a.ei = (const int*)d_in[1];
  a.ew = (const float*)d_in[2];
  a.W1 = (const float*)d_in[3];
  a.b1 = (const float*)d_in[4];
  a.W2 = (const float*)d_in[5];
  a.b2 = (const float*)d_in[6];
  a.W3 = (const float*)d_in[7];
  a.b3 = (const float*)d_in[8];
  a.out = (float*)d_out;

  const int N = N_NODES, E = N_EDGES;
  char* base = (char*)d_ws;
  size_t off = 0;
  auto alloc = [&](size_t bytes) -> char* {
    char* p = base + off;
    off += (bytes + 255) & ~(size_t)255;
    return p;
  };
  a.Yall = (float*)alloc((size_t)N * 768 * 4);   // 153.6 MB
  a.A = (float*)alloc((size_t)N * 128 * 4);
  a.B = (float*)alloc((size_t)N * 128 * 4);
  a.C = (float*)alloc((size_t)N * 128 * 4);
  a.D = (float*)alloc((size_t)N * 128 * 4);
  a.ptrA = (int*)alloc((size_t)(N + 1) * 4);
  a.pos  = (int*)alloc((size_t)N * 4);
  a.srcs = (int*)alloc((size_t)E * 4);
  a.wsrt = (float*)alloc((size_t)E * 4);
  a.bar  = (int*)alloc(256 * 4);

  // prep transients overlay A (A first written by the first layer-1 hop, after P5).
  // Yall must stay clear: layer-1 GEMM writes it during P1 (concurrent with prep).
  char* t = (char*)a.A;
  a.row32 = (int*)t;            t += (size_t)E * 4;
  a.col32 = (int*)t;            t += (size_t)E * 4;
  a.deg   = (float*)t;          t += (size_t)N * 4;
  a.dis   = (float*)t;          t += (size_t)N * 4;
  a.cnt   = (int*)t;            t += (size_t)N * 4;
  a.part  = (int*)t;            t += 2048 * 4;

  hipMemsetAsync(a.bar, 0, 256 * 4, stream);
  hipMemsetAsync(a.deg, 0, (size_t)N * 4, stream);
  hipMemsetAsync(a.cnt, 0, (size_t)N * 4, stream);

  int occ = 0;
  hipOccupancyMaxActiveBlocksPerMultiprocessor(&occ, (const void*)mega_kernel, 256, 0);
  int grid = occ * 256;
  if (grid > 1024) grid = 1024;
  if (grid < 64) grid = 64;

  void* args[] = { &a };
  hipLaunchCooperativeKernel((const void*)mega_kernel, dim3(grid), dim3(256), args, 0, stream);

  (void)in_sizes; (void)n_in; (void)out_size; (void)ws_size;
}

// Round 14
// 4875.752 us; speedup vs baseline: 3.2612x; 1.0202x over previous
//
#include <hip/hip_runtime.h>
#include <cstdint>
#include <cstddef>

#define N_NODES 50000
#define N_EDGES 800000
#define F_IN_D 100
#define HDIM 128
#define CDIM 10
#define NCH ((N_NODES + 255) / 256)   // 196 scan chunks

typedef unsigned short ushortT;

__device__ __forceinline__ float bf2f(unsigned int b16) {
  return __uint_as_float(b16 << 16);
}
__device__ __forceinline__ unsigned int f2bf(float f) {   // RNE bf16
  unsigned int u = __float_as_uint(f);
  unsigned int r = u + 0x7FFFu + ((u >> 16) & 1u);
  return r >> 16;
}

struct Args {
  const float* x; const int* ei; const float* ew;
  const float* W1; const float* b1;
  const float* W2; const float* b2;
  const float* W3; const float* b3;
  float* out;
  ushortT* Yall;                       // bf16 [N][768] = all six y_k of current layer
  char* A; char* B;                    // ping-pong: bf16 [N][128] (or fp32 [N][64] ybuf / z in layer 3)
  ushortT* C; ushortT* D;              // h1, h2 (bf16 [N][128])
  int* ptrA; int* pos; int* srcs; float* wsrt;
  int* row32; int* col32; float* deg; float* dis; int* cnt; int* part;
  int* bar;
};

// ---- grid barrier (R13-proven: leader-only fences + ACQUIRE poll; do not modify) ----
__device__ __forceinline__ void gbar(int* bar, int target) {
  __syncthreads();
  if (threadIdx.x == 0) {
    __threadfence();
    atomicAdd(bar, 1);
    while (__hip_atomic_load(bar, __ATOMIC_ACQUIRE, __HIP_MEMORY_SCOPE_AGENT) < target)
      __builtin_amdgcn_s_sleep(8);
    __threadfence();
  }
  __syncthreads();
}

// ---- GEMM tile: out[n0:+64, c0:+64] = X @ B (+bias if addb) ----
// XBF: X rows bf16.  OUTBF: write bf16 (uint2 of 4 bf16 per thread-row).
// BMODE 0: B[k,c]=W[k*128+c] (2 tiles/node-row). BMODE 1: W3 concat layout, 64-col tile.
template <int K_DIM, int BMODE, bool XBF, bool OUTBF>
__device__ __forceinline__ void gemm_tile(const void* __restrict__ Xv, const float* __restrict__ W,
                                          const float* __restrict__ bias, bool addb,
                                          void* __restrict__ outv, int ostride, int tile,
                                          float (&xt)[32][68], float (&bt)[32][64]) {
  const int tid = threadIdx.x;
  const int tx = tid & 15;
  const int ty = tid >> 4;
  int n0, c0;
  if (BMODE == 0) { n0 = (tile >> 1) * 64; c0 = (tile & 1) * 64; }
  else            { n0 = tile * 64;        c0 = 0; }
  float acc[4][4];
#pragma unroll
  for (int i = 0; i < 4; ++i)
#pragma unroll
    for (int j = 0; j < 4; ++j) acc[i][j] = 0.f;

  for (int k0 = 0; k0 < K_DIM; k0 += 32) {
#pragma unroll
    for (int i = 0; i < 8; ++i) {
      int idx = tid + i * 256;
      int nl = idx >> 5, kl = idx & 31;
      int nn = n0 + nl, kg = k0 + kl;
      float v = 0.f;
      if (nn < N_NODES && kg < K_DIM) {
        if (XBF) v = bf2f(((const ushortT*)Xv)[(size_t)nn * K_DIM + kg]);
        else     v = ((const float*)Xv)[(size_t)nn * K_DIM + kg];
      }
      xt[kl][nl] = v;
    }
#pragma unroll
    for (int i = 0; i < 8; ++i) {
      int idx = tid + i * 256;
      int kl = idx >> 6, cl = idx & 63;
      int kg = k0 + kl;
      float v = 0.f;
      if (BMODE == 0) {
        if (kg < K_DIM) v = W[(size_t)kg * 128 + c0 + cl];
      } else {
        if (kg < K_DIM && cl < 6 * CDIM)
          v = W[(size_t)(cl / CDIM) * (K_DIM * CDIM) + (size_t)kg * CDIM + (cl % CDIM)];
      }
      bt[kl][cl] = v;
    }
    __syncthreads();
#pragma unroll
    for (int kk = 0; kk < 32; ++kk) {
      float4 xv = *(const float4*)&xt[kk][tx * 4];
      float4 bv = *(const float4*)&bt[kk][ty * 4];
      acc[0][0] += xv.x * bv.x; acc[0][1] += xv.x * bv.y; acc[0][2] += xv.x * bv.z; acc[0][3] += xv.x * bv.w;
      acc[1][0] += xv.y * bv.x; acc[1][1] += xv.y * bv.y; acc[1][2] += xv.y * bv.z; acc[1][3] += xv.y * bv.w;
      acc[2][0] += xv.z * bv.x; acc[2][1] += xv.z * bv.y; acc[2][2] += xv.z * bv.z; acc[2][3] += xv.z * bv.w;
      acc[3][0] += xv.w * bv.x; acc[3][1] += xv.w * bv.y; acc[3][2] += xv.w * bv.z; acc[3][3] += xv.w * bv.w;
    }
    __syncthreads();
  }
#pragma unroll
  for (int i = 0; i < 4; ++i) {
    int nn = n0 + tx * 4 + i;
    if (nn >= N_NODES) continue;
#pragma unroll
    for (int j = 0; j < 4; ++j) {
      int c = c0 + ty * 4 + j;
      if (addb) {
        if (BMODE == 0) acc[i][j] += bias[c];
        else if (c < CDIM) acc[i][j] += bias[c];
      }
    }
    if (OUTBF) {
      uint2 o;
      o.x = f2bf(acc[i][0]) | (f2bf(acc[i][1]) << 16);
      o.y = f2bf(acc[i][2]) | (f2bf(acc[i][3]) << 16);
      *(uint2*)&((ushortT*)outv)[(size_t)nn * ostride + c0 + ty * 4] = o;
    } else {
#pragma unroll
      for (int j = 0; j < 4; ++j)
        ((float*)outv)[(size_t)nn * ostride + c0 + ty * 4 + j] = acc[i][j];
    }
  }
}

// ---- bf16 hop d=128: Q[n] = maybeELU( Y[n] + sum_j w_j * P[src_j] ) ----
// Rows are 128 bf16 = 32 x uint2. pstr/ystr in uint2 units (192 for Yall rows, 32 for ping bufs).
template <bool ELU>
__device__ __forceinline__ void hopb_phase(const uint2* __restrict__ P2, int pstr,
                                           const uint2* __restrict__ Y2, int ystr,
                                           const int* __restrict__ ptr, const int* __restrict__ srcs,
                                           const float* __restrict__ w, uint2* __restrict__ Q2) {
  const int lane = threadIdx.x & 63;
  const int wid = threadIdx.x >> 6;
  const int half = lane >> 5;
  const int f4 = lane & 31;
  for (int node = blockIdx.x * 4 + wid; node < N_NODES; node += gridDim.x * 4) {
    const int b = ptr[node], e = ptr[node + 1];
    const int len = e - b;
    const int c0 = (len + 1) >> 1;
    const int js = half ? (b + c0) : b;
    const int je = half ? e : (b + c0);
    float a0 = 0.f, a1 = 0.f, a2 = 0.f, a3 = 0.f;
    if (half == 0) {
      uint2 yv = Y2[(size_t)node * ystr + f4];
      a0 = bf2f(yv.x & 0xFFFFu); a1 = bf2f(yv.x >> 16);
      a2 = bf2f(yv.y & 0xFFFFu); a3 = bf2f(yv.y >> 16);
    }
    int j = js;
    for (; j + 3 < je; j += 4) {
      int s0 = srcs[j], s1 = srcs[j + 1], s2 = srcs[j + 2], s3 = srcs[j + 3];
      float w0 = w[j], w1 = w[j + 1], w2 = w[j + 2], w3 = w[j + 3];
      uint2 v0 = P2[(size_t)s0 * pstr + f4];
      uint2 v1 = P2[(size_t)s1 * pstr + f4];
      uint2 v2 = P2[(size_t)s2 * pstr + f4];
      uint2 v3 = P2[(size_t)s3 * pstr + f4];
      a0 += w0 * bf2f(v0.x & 0xFFFFu) + w1 * bf2f(v1.x & 0xFFFFu) + w2 * bf2f(v2.x & 0xFFFFu) + w3 * bf2f(v3.x & 0xFFFFu);
      a1 += w0 * bf2f(v0.x >> 16)     + w1 * bf2f(v1.x >> 16)     + w2 * bf2f(v2.x >> 16)     + w3 * bf2f(v3.x >> 16);
      a2 += w0 * bf2f(v0.y & 0xFFFFu) + w1 * bf2f(v1.y & 0xFFFFu) + w2 * bf2f(v2.y & 0xFFFFu) + w3 * bf2f(v3.y & 0xFFFFu);
      a3 += w0 * bf2f(v0.y >> 16)     + w1 * bf2f(v1.y >> 16)     + w2 * bf2f(v2.y >> 16)     + w3 * bf2f(v3.y >> 16);
    }
    for (; j < je; ++j) {
      float w0 = w[j];
      uint2 v0 = P2[(size_t)srcs[j] * pstr + f4];
      a0 += w0 * bf2f(v0.x & 0xFFFFu);
      a1 += w0 * bf2f(v0.x >> 16);
      a2 += w0 * bf2f(v0.y & 0xFFFFu);
      a3 += w0 * bf2f(v0.y >> 16);
    }
    a0 += __shfl_xor(a0, 32);
    a1 += __shfl_xor(a1, 32);
    a2 += __shfl_xor(a2, 32);
    a3 += __shfl_xor(a3, 32);
    if (half == 0) {
      if (ELU) {
        a0 = a0 > 0.f ? a0 : expm1f(a0);
        a1 = a1 > 0.f ? a1 : expm1f(a1);
        a2 = a2 > 0.f ? a2 : expm1f(a2);
        a3 = a3 > 0.f ? a3 : expm1f(a3);
      }
      uint2 o;
      o.x = f2bf(a0) | (f2bf(a1) << 16);
      o.y = f2bf(a2) | (f2bf(a3) << 16);
      Q2[(size_t)node * 32 + f4] = o;
    }
  }
}

// ---- hop d=10 (fp32, unchanged) ----
__device__ __forceinline__ void hop10_phase(const float* __restrict__ z, int zStride, int zOff,
                                            const float* __restrict__ ybuf, int yOff,
                                            const int* __restrict__ ptr, const int* __restrict__ srcs,
                                            const float* __restrict__ wsrt, float* __restrict__ outp) {
  const int lane = threadIdx.x & 63;
  const int wid = threadIdx.x >> 6;
  const int sub = lane >> 4;
  const int f = lane & 15;
  for (int node = blockIdx.x * 4 + wid; node < N_NODES; node += gridDim.x * 4) {
    const int b = ptr[node], e = ptr[node + 1];
    const int len = e - b;
    const int js = b + (len * sub) / 4;
    const int je = b + (len * (sub + 1)) / 4;
    float acc = 0.f;
    if (f < CDIM) {
      if (sub == 0) acc = ybuf[(size_t)node * 64 + yOff + f];
      int j = js;
      for (; j + 1 < je; j += 2) {
        int s0 = srcs[j], s1 = srcs[j + 1];
        float w0 = wsrt[j], w1 = wsrt[j + 1];
        acc += w0 * z[(size_t)s0 * zStride + zOff + f] + w1 * z[(size_t)s1 * zStride + zOff + f];
      }
      if (j < je) acc += wsrt[j] * z[(size_t)srcs[j] * zStride + zOff + f];
    }
    acc += __shfl_xor(acc, 16);
    acc += __shfl_xor(acc, 32);
    if (sub == 0 && f < CDIM) outp[(size_t)node * CDIM + f] = acc;
  }
}

// ================= persistent kernel, 21 barriers =================
__global__ __launch_bounds__(256, 4) void mega_kernel(Args a) {
  __shared__ float xt[32][68];
  __shared__ float bt[32][64];
  __shared__ int sdi[256];
  const int tid = threadIdx.x;
  const int gtid = blockIdx.x * blockDim.x + tid;
  const int gstride = gridDim.x * blockDim.x;
  const int gdim = gridDim.x;
  const int TG0 = ((N_NODES + 63) / 64) * 2;   // 1564 tiles per 128-col GEMM
  const int TG1 = (N_NODES + 63) / 64;         // 782
  int nb = 0;

  // P1: convert edges + degree atomics, then layer-1 GEMM (independent of prep)
  {
    bool is64 = true;
    for (int i = 0; i < 32; ++i) if (a.ei[2 * i + 1] != 0) is64 = false;
    for (int e = gtid; e < N_EDGES; e += gstride) {
      int r, c;
      if (is64) { r = a.ei[2 * e]; c = a.ei[2 * (N_EDGES + e)]; }
      else      { r = a.ei[e];     c = a.ei[N_EDGES + e]; }
      a.row32[e] = r; a.col32[e] = c;
      atomicAdd(&a.deg[c], a.ew[e]);
      atomicAdd(&a.cnt[c], 1);
    }
  }
  for (int job = blockIdx.x; job < 6 * TG0; job += gdim) {
    int k = job / TG0, t = job % TG0;
    gemm_tile<F_IN_D, 0, false, true>(a.x, a.W1 + (size_t)k * F_IN_D * 128, a.b1, k == 0,
                                      a.Yall + k * 128, 768, t, xt, bt);
  }
  gbar(a.bar, (++nb) * gdim);

  // P2: dis + per-chunk count sums
  for (int i = gtid; i < N_NODES; i += gstride) {
    float d = a.deg[i];
    a.dis[i] = d > 0.f ? rsqrtf(fmaxf(d, 1e-12f)) : 0.f;
  }
  for (int c = blockIdx.x; c < NCH; c += gdim) {
    int i = c * 256 + tid;
    sdi[tid] = (i < N_NODES) ? a.cnt[i] : 0;
    __syncthreads();
    for (int s = 128; s > 0; s >>= 1) { if (tid < s) sdi[tid] += sdi[tid + s]; __syncthreads(); }
    if (tid == 0) a.part[c] = sdi[0];
    __syncthreads();
  }
  gbar(a.bar, (++nb) * gdim);

  // P3: block 0 scans the 196 partials
  if (blockIdx.x == 0) {
    int v = (tid < NCH) ? a.part[tid] : 0;
    sdi[tid] = v;
    __syncthreads();
    for (int o = 1; o < 256; o <<= 1) {
      int t2 = (tid >= o) ? sdi[tid - o] : 0;
      __syncthreads();
      sdi[tid] += t2;
      __syncthreads();
    }
    if (tid < NCH) a.part[tid] = sdi[tid] - v;
    if (tid == 255) a.ptrA[N_NODES] = sdi[255];
  }
  gbar(a.bar, (++nb) * gdim);

  // P4: per-chunk exclusive scan -> ptrA, pos
  for (int c = blockIdx.x; c < NCH; c += gdim) {
    int i = c * 256 + tid;
    int v = (i < N_NODES) ? a.cnt[i] : 0;
    sdi[tid] = v;
    __syncthreads();
    for (int o = 1; o < 256; o <<= 1) {
      int t2 = (tid >= o) ? sdi[tid - o] : 0;
      __syncthreads();
      sdi[tid] += t2;
      __syncthreads();
    }
    if (i < N_NODES) { int p = a.part[c] + sdi[tid] - v; a.ptrA[i] = p; a.pos[i] = p; }
    __syncthreads();
  }
  gbar(a.bar, (++nb) * gdim);

  // P5: place into CSC + fused norm
  for (int e = gtid; e < N_EDGES; e += gstride) {
    int r = a.row32[e], c = a.col32[e];
    int slot = atomicAdd(&a.pos[c], 1);
    a.srcs[slot] = r;
    a.wsrt[slot] = a.dis[r] * a.ew[e] * a.dis[c];
  }
  gbar(a.bar, (++nb) * gdim);

  const uint2* Y2 = (const uint2*)a.Yall;      // row stride 192 uint2; y_k at offset k*32
  uint2* A2 = (uint2*)a.A; uint2* B2 = (uint2*)a.B;
  uint2* C2 = (uint2*)a.C; uint2* D2 = (uint2*)a.D;

  // ===== layer 1 hops (y_k already in Yall, bf16) =====
  hopb_phase<false>(Y2 + 5 * 32, 192, Y2 + 4 * 32, 192, a.ptrA, a.srcs, a.wsrt, A2);
  gbar(a.bar, (++nb) * gdim);
  hopb_phase<false>(A2, 32, Y2 + 3 * 32, 192, a.ptrA, a.srcs, a.wsrt, B2);
  gbar(a.bar, (++nb) * gdim);
  hopb_phase<false>(B2, 32, Y2 + 2 * 32, 192, a.ptrA, a.srcs, a.wsrt, A2);
  gbar(a.bar, (++nb) * gdim);
  hopb_phase<false>(A2, 32, Y2 + 1 * 32, 192, a.ptrA, a.srcs, a.wsrt, B2);
  gbar(a.bar, (++nb) * gdim);
  hopb_phase<true>(B2, 32, Y2 + 0 * 32, 192, a.ptrA, a.srcs, a.wsrt, C2);
  gbar(a.bar, (++nb) * gdim);
  // h1 = C (bf16)

  // ===== layer 2: GEMM (X = C bf16) then hops =====
  for (int job = blockIdx.x; job < 6 * TG0; job += gdim) {
    int k = job / TG0, t = job % TG0;
    gemm_tile<HDIM, 0, true, true>(a.C, a.W2 + (size_t)k * HDIM * 128, a.b2, k == 0,
                                   a.Yall + k * 128, 768, t, xt, bt);
  }
  gbar(a.bar, (++nb) * gdim);
  hopb_phase<false>(Y2 + 5 * 32, 192, Y2 + 4 * 32, 192, a.ptrA, a.srcs, a.wsrt, A2);
  gbar(a.bar, (++nb) * gdim);
  hopb_phase<false>(A2, 32, Y2 + 3 * 32, 192, a.ptrA, a.srcs, a.wsrt, B2);
  gbar(a.bar, (++nb) * gdim);
  hopb_phase<false>(B2, 32, Y2 + 2 * 32, 192, a.ptrA, a.srcs, a.wsrt, A2);
  gbar(a.bar, (++nb) * gdim);
  hopb_phase<false>(A2, 32, Y2 + 1 * 32, 192, a.ptrA, a.srcs, a.wsrt, B2);
  gbar(a.bar, (++nb) * gdim);
  hopb_phase<true>(B2, 32, Y2 + 0 * 32, 192, a.ptrA, a.srcs, a.wsrt, D2);
  gbar(a.bar, (++nb) * gdim);
  // h2 = D (bf16)

  // ===== layer 3: GEMM (X = D bf16 -> fp32 ybuf = A [N][64]) then hop10 chain =====
  float* ybuf = (float*)a.A;
  float* z0 = (float*)a.B;
  float* z1 = (float*)(a.B + (size_t)N_NODES * 16 * 4);
  for (int t = blockIdx.x; t < TG1; t += gdim)
    gemm_tile<HDIM, 1, true, false>(a.D, a.W3, a.b3, true, ybuf, 64, t, xt, bt);
  gbar(a.bar, (++nb) * gdim);
  hop10_phase(ybuf, 64, 50, ybuf, 40, a.ptrA, a.srcs, a.wsrt, z0); gbar(a.bar, (++nb) * gdim);
  hop10_phase(z0, 10, 0, ybuf, 30, a.ptrA, a.srcs, a.wsrt, z1); gbar(a.bar, (++nb) * gdim);
  hop10_phase(z1, 10, 0, ybuf, 20, a.ptrA, a.srcs, a.wsrt, z0); gbar(a.bar, (++nb) * gdim);
  hop10_phase(z0, 10, 0, ybuf, 10, a.ptrA, a.srcs, a.wsrt, z1); gbar(a.bar, (++nb) * gdim);
  hop10_phase(z1, 10, 0, ybuf, 0, a.ptrA, a.srcs, a.wsrt, a.out);
}

// ---------------- host ----------------

extern "C" void kernel_launch(void* const* d_in, const int* in_sizes, int n_in,
                              void* d_out, int out_size, void* d_ws, size_t ws_size,
                              hipStream_t stream) {
  Args a;
  a.x  = (const float*)d_in[0];
  a.ei = (const int*)d_in[1];
  a.ew = (const float*)d_in[2];
  a.W1 = (const float*)d_in[3];
  a.b1 = (const float*)d_in[4];
  a.W2 = (const float*)d_in[5];
  a.b2 = (const float*)d_in[6];
  a.W3 = (const float*)d_in[7];
  a.b3 = (const float*)d_in[8];
  a.out = (float*)d_out;

  const int N = N_NODES, E = N_EDGES;
  char* base = (char*)d_ws;
  size_t off = 0;
  auto alloc = [&](size_t bytes) -> char* {
    char* p = base + off;
    off += (bytes + 255) & ~(size_t)255;
    return p;
  };
  a.Yall = (ushortT*)alloc((size_t)N * 768 * 2);   // 76.8 MB (bf16)
  a.A = alloc((size_t)N * 256);                    // bf16 [N][128] or fp32 [N][64]
  a.B = alloc((size_t)N * 256);
  a.C = (ushortT*)alloc((size_t)N * 128 * 2);
  a.D = (ushortT*)alloc((size_t)N * 128 * 2);
  a.ptrA = (int*)alloc((size_t)(N + 1) * 4);
  a.pos  = (int*)alloc((size_t)N * 4);
  a.srcs = (int*)alloc((size_t)E * 4);
  a.wsrt = (float*)alloc((size_t)E * 4);
  a.bar  = (int*)alloc(256 * 4);

  // prep transients overlay A (A first written by the first layer-1 hop, after P5).
  // Yall stays clear: layer-1 GEMM writes it during P1 (concurrent with prep).
  char* t = a.A;
  a.row32 = (int*)t;            t += (size_t)E * 4;
  a.col32 = (int*)t;            t += (size_t)E * 4;
  a.deg   = (float*)t;          t += (size_t)N * 4;
  a.dis   = (float*)t;          t += (size_t)N * 4;
  a.cnt   = (int*)t;            t += (size_t)N * 4;
  a.part  = (int*)t;            t += 2048 * 4;

  hipMemsetAsync(a.bar, 0, 256 * 4, stream);
  hipMemsetAsync(a.deg, 0, (size_t)N * 4, stream);
  hipMemsetAsync(a.cnt, 0, (size_t)N * 4, stream);

  int occ = 0;
  hipOccupancyMaxActiveBlocksPerMultiprocessor(&occ, (const void*)mega_kernel, 256, 0);
  int grid = occ * 256;
  if (grid > 1024) grid = 1024;
  if (grid < 64) grid = 64;

  void* args[] = { &a };
  hipLaunchCooperativeKernel((const void*)mega_kernel, dim3(grid), dim3(256), args, 0, stream);

  (void)in_sizes; (void)n_in; (void)out_size; (void)ws_size;
}

// Round 15
// 4224.614 us; speedup vs baseline: 3.7638x; 1.1541x over previous
//
#include <hip/hip_runtime.h>
#include <cstdint>
#include <cstddef>

#define N_NODES 50000
#define N_EDGES 800000
#define F_IN_D 100
#define HDIM 128
#define CDIM 10
#define NCH ((N_NODES + 255) / 256)   // 196 scan chunks
#define NLINES 32                     // barrier arrival lines (padded cache lines)

typedef unsigned short ushortT;

__device__ __forceinline__ float bf2f(unsigned int b16) {
  return __uint_as_float(b16 << 16);
}
__device__ __forceinline__ unsigned int f2bf(float f) {   // RNE bf16
  unsigned int u = __float_as_uint(f);
  unsigned int r = u + 0x7FFFu + ((u >> 16) & 1u);
  return r >> 16;
}

struct Args {
  const float* x; const int* ei; const float* ew;
  const float* W1; const float* b1;
  const float* W2; const float* b2;
  const float* W3; const float* b3;
  float* out;
  ushortT* Yall;                       // bf16 [N][768]
  char* A; char* B;                    // bf16 [N][128] ping-pong (fp32 [N][64] ybuf / z in layer 3)
  ushortT* C; ushortT* D;              // h1, h2 (bf16 [N][128])
  int* ptrA; int* pos; int* srcs; float* wsrt;
  int* row32; int* col32; float* deg; float* dis; int* cnt; int* part;
  int* lines;                          // NLINES padded arrival counters (host-zeroed)
  int* gbl;                            // global phase counter (host-zeroed)
};

// ---- grid barrier v4: two-level arrival (32 padded lines), ACQUIRE poll (R13-proven) ----
// gdim MUST be a multiple of NLINES. Each line receives gdim/NLINES arrivals per round;
// the last arriver on a line (atomicAdd old == round*perLine - 1) bumps the global
// counter once. All blocks poll the single global counter with ACQUIRE (RELAXED hangs - R11).
__device__ __forceinline__ void gbar(int* lines, int* gbl, int round, int gdim) {
  __syncthreads();
  if (threadIdx.x == 0) {
    __threadfence();                                   // release
    const int perLine = gdim >> 5;                     // gdim / NLINES
    int old = atomicAdd(&lines[(blockIdx.x & (NLINES - 1)) * 32], 1);
    if (old == round * perLine - 1) atomicAdd(gbl, 1);
    while (__hip_atomic_load(gbl, __ATOMIC_ACQUIRE, __HIP_MEMORY_SCOPE_AGENT) < round * NLINES)
      __builtin_amdgcn_s_sleep(8);
    __threadfence();                                   // acquire
  }
  __syncthreads();
}

// ---- GEMM tile: out[n0:+64, c0:+64] = X @ B (+bias if addb) ----
template <int K_DIM, int BMODE, bool XBF, bool OUTBF>
__device__ __forceinline__ void gemm_tile(const void* __restrict__ Xv, const float* __restrict__ W,
                                          const float* __restrict__ bias, bool addb,
                                          void* __restrict__ outv, int ostride, int tile,
                                          float (&xt)[32][68], float (&bt)[32][64]) {
  const int tid = threadIdx.x;
  const int tx = tid & 15;
  const int ty = tid >> 4;
  int n0, c0;
  if (BMODE == 0) { n0 = (tile >> 1) * 64; c0 = (tile & 1) * 64; }
  else            { n0 = tile * 64;        c0 = 0; }
  float acc[4][4];
#pragma unroll
  for (int i = 0; i < 4; ++i)
#pragma unroll
    for (int j = 0; j < 4; ++j) acc[i][j] = 0.f;

  for (int k0 = 0; k0 < K_DIM; k0 += 32) {
#pragma unroll
    for (int i = 0; i < 8; ++i) {
      int idx = tid + i * 256;
      int nl = idx >> 5, kl = idx & 31;
      int nn = n0 + nl, kg = k0 + kl;
      float v = 0.f;
      if (nn < N_NODES && kg < K_DIM) {
        if (XBF) v = bf2f(((const ushortT*)Xv)[(size_t)nn * K_DIM + kg]);
        else     v = ((const float*)Xv)[(size_t)nn * K_DIM + kg];
      }
      xt[kl][nl] = v;
    }
#pragma unroll
    for (int i = 0; i < 8; ++i) {
      int idx = tid + i * 256;
      int kl = idx >> 6, cl = idx & 63;
      int kg = k0 + kl;
      float v = 0.f;
      if (BMODE == 0) {
        if (kg < K_DIM) v = W[(size_t)kg * 128 + c0 + cl];
      } else {
        if (kg < K_DIM && cl < 6 * CDIM)
          v = W[(size_t)(cl / CDIM) * (K_DIM * CDIM) + (size_t)kg * CDIM + (cl % CDIM)];
      }
      bt[kl][cl] = v;
    }
    __syncthreads();
#pragma unroll
    for (int kk = 0; kk < 32; ++kk) {
      float4 xv = *(const float4*)&xt[kk][tx * 4];
      float4 bv = *(const float4*)&bt[kk][ty * 4];
      acc[0][0] += xv.x * bv.x; acc[0][1] += xv.x * bv.y; acc[0][2] += xv.x * bv.z; acc[0][3] += xv.x * bv.w;
      acc[1][0] += xv.y * bv.x; acc[1][1] += xv.y * bv.y; acc[1][2] += xv.y * bv.z; acc[1][3] += xv.y * bv.w;
      acc[2][0] += xv.z * bv.x; acc[2][1] += xv.z * bv.y; acc[2][2] += xv.z * bv.z; acc[2][3] += xv.z * bv.w;
      acc[3][0] += xv.w * bv.x; acc[3][1] += xv.w * bv.y; acc[3][2] += xv.w * bv.z; acc[3][3] += xv.w * bv.w;
    }
    __syncthreads();
  }
#pragma unroll
  for (int i = 0; i < 4; ++i) {
    int nn = n0 + tx * 4 + i;
    if (nn >= N_NODES) continue;
#pragma unroll
    for (int j = 0; j < 4; ++j) {
      int c = c0 + ty * 4 + j;
      if (addb) {
        if (BMODE == 0) acc[i][j] += bias[c];
        else if (c < CDIM) acc[i][j] += bias[c];
      }
    }
    if (OUTBF) {
      uint2 o;
      o.x = f2bf(acc[i][0]) | (f2bf(acc[i][1]) << 16);
      o.y = f2bf(acc[i][2]) | (f2bf(acc[i][3]) << 16);
      *(uint2*)&((ushortT*)outv)[(size_t)nn * ostride + c0 + ty * 4] = o;
    } else {
#pragma unroll
      for (int j = 0; j < 4; ++j)
        ((float*)outv)[(size_t)nn * ostride + c0 + ty * 4 + j] = acc[i][j];
    }
  }
}

// ---- bf16 hop d=128, half-wave per node, 8-deep gather pipeline ----
// A bf16 row = 128*2 B = 32 lanes x uint2: one 32-lane half-wave covers a full row.
// No cross-lane combine; 8 independent gathers in flight per half-wave (16/wave).
template <bool ELU>
__device__ __forceinline__ void hopb_phase(const uint2* __restrict__ P2, int pstr,
                                           const uint2* __restrict__ Y2, int ystr,
                                           const int* __restrict__ ptr, const int* __restrict__ srcs,
                                           const float* __restrict__ w, uint2* __restrict__ Q2) {
  const int hw = threadIdx.x >> 5;             // 8 half-waves per 256-thread block
  const int f4 = threadIdx.x & 31;
  for (int node = blockIdx.x * 8 + hw; node < N_NODES; node += gridDim.x * 8) {
    const int b = ptr[node], e = ptr[node + 1];
    uint2 yv = Y2[(size_t)node * ystr + f4];
    float a0 = bf2f(yv.x & 0xFFFFu), a1 = bf2f(yv.x >> 16);
    float a2 = bf2f(yv.y & 0xFFFFu), a3 = bf2f(yv.y >> 16);
    int j = b;
    for (; j + 7 < e; j += 8) {
      int s0 = srcs[j], s1 = srcs[j + 1], s2 = srcs[j + 2], s3 = srcs[j + 3];
      int s4 = srcs[j + 4], s5 = srcs[j + 5], s6 = srcs[j + 6], s7 = srcs[j + 7];
      float w0 = w[j], w1 = w[j + 1], w2 = w[j + 2], w3 = w[j + 3];
      float w4 = w[j + 4], w5 = w[j + 5], w6 = w[j + 6], w7 = w[j + 7];
      uint2 v0 = P2[(size_t)s0 * pstr + f4];
      uint2 v1 = P2[(size_t)s1 * pstr + f4];
      uint2 v2 = P2[(size_t)s2 * pstr + f4];
      uint2 v3 = P2[(size_t)s3 * pstr + f4];
      uint2 v4 = P2[(size_t)s4 * pstr + f4];
      uint2 v5 = P2[(size_t)s5 * pstr + f4];
      uint2 v6 = P2[(size_t)s6 * pstr + f4];
      uint2 v7 = P2[(size_t)s7 * pstr + f4];
      a0 += w0 * bf2f(v0.x & 0xFFFFu) + w1 * bf2f(v1.x & 0xFFFFu) + w2 * bf2f(v2.x & 0xFFFFu) + w3 * bf2f(v3.x & 0xFFFFu)
          + w4 * bf2f(v4.x & 0xFFFFu) + w5 * bf2f(v5.x & 0xFFFFu) + w6 * bf2f(v6.x & 0xFFFFu) + w7 * bf2f(v7.x & 0xFFFFu);
      a1 += w0 * bf2f(v0.x >> 16) + w1 * bf2f(v1.x >> 16) + w2 * bf2f(v2.x >> 16) + w3 * bf2f(v3.x >> 16)
          + w4 * bf2f(v4.x >> 16) + w5 * bf2f(v5.x >> 16) + w6 * bf2f(v6.x >> 16) + w7 * bf2f(v7.x >> 16);
      a2 += w0 * bf2f(v0.y & 0xFFFFu) + w1 * bf2f(v1.y & 0xFFFFu) + w2 * bf2f(v2.y & 0xFFFFu) + w3 * bf2f(v3.y & 0xFFFFu)
          + w4 * bf2f(v4.y & 0xFFFFu) + w5 * bf2f(v5.y & 0xFFFFu) + w6 * bf2f(v6.y & 0xFFFFu) + w7 * bf2f(v7.y & 0xFFFFu);
      a3 += w0 * bf2f(v0.y >> 16) + w1 * bf2f(v1.y >> 16) + w2 * bf2f(v2.y >> 16) + w3 * bf2f(v3.y >> 16)
          + w4 * bf2f(v4.y >> 16) + w5 * bf2f(v5.y >> 16) + w6 * bf2f(v6.y >> 16) + w7 * bf2f(v7.y >> 16);
    }
    for (; j + 1 < e; j += 2) {
      int s0 = srcs[j], s1 = srcs[j + 1];
      float w0 = w[j], w1 = w[j + 1];
      uint2 v0 = P2[(size_t)s0 * pstr + f4];
      uint2 v1 = P2[(size_t)s1 * pstr + f4];
      a0 += w0 * bf2f(v0.x & 0xFFFFu) + w1 * bf2f(v1.x & 0xFFFFu);
      a1 += w0 * bf2f(v0.x >> 16)     + w1 * bf2f(v1.x >> 16);
      a2 += w0 * bf2f(v0.y & 0xFFFFu) + w1 * bf2f(v1.y & 0xFFFFu);
      a3 += w0 * bf2f(v0.y >> 16)     + w1 * bf2f(v1.y >> 16);
    }
    if (j < e) {
      float w0 = w[j];
      uint2 v0 = P2[(size_t)srcs[j] * pstr + f4];
      a0 += w0 * bf2f(v0.x & 0xFFFFu);
      a1 += w0 * bf2f(v0.x >> 16);
      a2 += w0 * bf2f(v0.y & 0xFFFFu);
      a3 += w0 * bf2f(v0.y >> 16);
    }
    if (ELU) {
      a0 = a0 > 0.f ? a0 : expm1f(a0);
      a1 = a1 > 0.f ? a1 : expm1f(a1);
      a2 = a2 > 0.f ? a2 : expm1f(a2);
      a3 = a3 > 0.f ? a3 : expm1f(a3);
    }
    uint2 o;
    o.x = f2bf(a0) | (f2bf(a1) << 16);
    o.y = f2bf(a2) | (f2bf(a3) << 16);
    Q2[(size_t)node * 32 + f4] = o;
  }
}

// ---- hop d=10 (fp32, unchanged) ----
__device__ __forceinline__ void hop10_phase(const float* __restrict__ z, int zStride, int zOff,
                                            const float* __restrict__ ybuf, int yOff,
                                            const int* __restrict__ ptr, const int* __restrict__ srcs,
                                            const float* __restrict__ wsrt, float* __restrict__ outp) {
  const int lane = threadIdx.x & 63;
  const int wid = threadIdx.x >> 6;
  const int sub = lane >> 4;
  const int f = lane & 15;
  for (int node = blockIdx.x * 4 + wid; node < N_NODES; node += gridDim.x * 4) {
    const int b = ptr[node], e = ptr[node + 1];
    const int len = e - b;
    const int js = b + (len * sub) / 4;
    const int je = b + (len * (sub + 1)) / 4;
    float acc = 0.f;
    if (f < CDIM) {
      if (sub == 0) acc = ybuf[(size_t)node * 64 + yOff + f];
      int j = js;
      for (; j + 1 < je; j += 2) {
        int s0 = srcs[j], s1 = srcs[j + 1];
        float w0 = wsrt[j], w1 = wsrt[j + 1];
        acc += w0 * z[(size_t)s0 * zStride + zOff + f] + w1 * z[(size_t)s1 * zStride + zOff + f];
      }
      if (j < je) acc += wsrt[j] * z[(size_t)srcs[j] * zStride + zOff + f];
    }
    acc += __shfl_xor(acc, 16);
    acc += __shfl_xor(acc, 32);
    if (sub == 0 && f < CDIM) outp[(size_t)node * CDIM + f] = acc;
  }
}

// ================= persistent kernel, 21 barriers =================
__global__ __launch_bounds__(256, 4) void mega_kernel(Args a) {
  __shared__ float xt[32][68];
  __shared__ float bt[32][64];
  __shared__ int sdi[256];
  const int tid = threadIdx.x;
  const int gtid = blockIdx.x * blockDim.x + tid;
  const int gstride = gridDim.x * blockDim.x;
  const int gdim = gridDim.x;
  const int TG0 = ((N_NODES + 63) / 64) * 2;   // 1564
  const int TG1 = (N_NODES + 63) / 64;         // 782
  int nb = 0;

  // P1: convert edges + degree atomics, then layer-1 GEMM (independent of prep)
  {
    bool is64 = true;
    for (int i = 0; i < 32; ++i) if (a.ei[2 * i + 1] != 0) is64 = false;
    for (int e = gtid; e < N_EDGES; e += gstride) {
      int r, c;
      if (is64) { r = a.ei[2 * e]; c = a.ei[2 * (N_EDGES + e)]; }
      else      { r = a.ei[e];     c = a.ei[N_EDGES + e]; }
      a.row32[e] = r; a.col32[e] = c;
      atomicAdd(&a.deg[c], a.ew[e]);
      atomicAdd(&a.cnt[c], 1);
    }
  }
  for (int job = blockIdx.x; job < 6 * TG0; job += gdim) {
    int k = job / TG0, t = job % TG0;
    gemm_tile<F_IN_D, 0, false, true>(a.x, a.W1 + (size_t)k * F_IN_D * 128, a.b1, k == 0,
                                      a.Yall + k * 128, 768, t, xt, bt);
  }
  gbar(a.lines, a.gbl, ++nb, gdim);

  // P2: dis + per-chunk count sums
  for (int i = gtid; i < N_NODES; i += gstride) {
    float d = a.deg[i];
    a.dis[i] = d > 0.f ? rsqrtf(fmaxf(d, 1e-12f)) : 0.f;
  }
  for (int c = blockIdx.x; c < NCH; c += gdim) {
    int i = c * 256 + tid;
    sdi[tid] = (i < N_NODES) ? a.cnt[i] : 0;
    __syncthreads();
    for (int s = 128; s > 0; s >>= 1) { if (tid < s) sdi[tid] += sdi[tid + s]; __syncthreads(); }
    if (tid == 0) a.part[c] = sdi[0];
    __syncthreads();
  }
  gbar(a.lines, a.gbl, ++nb, gdim);

  // P3: block 0 scans the 196 partials
  if (blockIdx.x == 0) {
    int v = (tid < NCH) ? a.part[tid] : 0;
    sdi[tid] = v;
    __syncthreads();
    for (int o = 1; o < 256; o <<= 1) {
      int t2 = (tid >= o) ? sdi[tid - o] : 0;
      __syncthreads();
      sdi[tid] += t2;
      __syncthreads();
    }
    if (tid < NCH) a.part[tid] = sdi[tid] - v;
    if (tid == 255) a.ptrA[N_NODES] = sdi[255];
  }
  gbar(a.lines, a.gbl, ++nb, gdim);

  // P4: per-chunk exclusive scan -> ptrA, pos
  for (int c = blockIdx.x; c < NCH; c += gdim) {
    int i = c * 256 + tid;
    int v = (i < N_NODES) ? a.cnt[i] : 0;
    sdi[tid] = v;
    __syncthreads();
    for (int o = 1; o < 256; o <<= 1) {
      int t2 = (tid >= o) ? sdi[tid - o] : 0;
      __syncthreads();
      sdi[tid] += t2;
      __syncthreads();
    }
    if (i < N_NODES) { int p = a.part[c] + sdi[tid] - v; a.ptrA[i] = p; a.pos[i] = p; }
    __syncthreads();
  }
  gbar(a.lines, a.gbl, ++nb, gdim);

  // P5: place into CSC + fused norm
  for (int e = gtid; e < N_EDGES; e += gstride) {
    int r = a.row32[e], c = a.col32[e];
    int slot = atomicAdd(&a.pos[c], 1);
    a.srcs[slot] = r;
    a.wsrt[slot] = a.dis[r] * a.ew[e] * a.dis[c];
  }
  gbar(a.lines, a.gbl, ++nb, gdim);

  const uint2* Y2 = (const uint2*)a.Yall;      // row stride 192 uint2; y_k at offset k*32
  uint2* A2 = (uint2*)a.A; uint2* B2 = (uint2*)a.B;
  uint2* C2 = (uint2*)a.C; uint2* D2 = (uint2*)a.D;

  // ===== layer 1 hops =====
  hopb_phase<false>(Y2 + 5 * 32, 192, Y2 + 4 * 32, 192, a.ptrA, a.srcs, a.wsrt, A2);
  gbar(a.lines, a.gbl, ++nb, gdim);
  hopb_phase<false>(A2, 32, Y2 + 3 * 32, 192, a.ptrA, a.srcs, a.wsrt, B2);
  gbar(a.lines, a.gbl, ++nb, gdim);
  hopb_phase<false>(B2, 32, Y2 + 2 * 32, 192, a.ptrA, a.srcs, a.wsrt, A2);
  gbar(a.lines, a.gbl, ++nb, gdim);
  hopb_phase<false>(A2, 32, Y2 + 1 * 32, 192, a.ptrA, a.srcs, a.wsrt, B2);
  gbar(a.lines, a.gbl, ++nb, gdim);
  hopb_phase<true>(B2, 32, Y2 + 0 * 32, 192, a.ptrA, a.srcs, a.wsrt, C2);
  gbar(a.lines, a.gbl, ++nb, gdim);
  // h1 = C (bf16)

  // ===== layer 2: GEMM (X = C bf16) then hops =====
  for (int job = blockIdx.x; job < 6 * TG0; job += gdim) {
    int k = job / TG0, t = job % TG0;
    gemm_tile<HDIM, 0, true, true>(a.C, a.W2 + (size_t)k * HDIM * 128, a.b2, k == 0,
                                   a.Yall + k * 128, 768, t, xt, bt);
  }
  gbar(a.lines, a.gbl, ++nb, gdim);
  hopb_phase<false>(Y2 + 5 * 32, 192, Y2 + 4 * 32, 192, a.ptrA, a.srcs, a.wsrt, A2);
  gbar(a.lines, a.gbl, ++nb, gdim);
  hopb_phase<false>(A2, 32, Y2 + 3 * 32, 192, a.ptrA, a.srcs, a.wsrt, B2);
  gbar(a.lines, a.gbl, ++nb, gdim);
  hopb_phase<false>(B2, 32, Y2 + 2 * 32, 192, a.ptrA, a.srcs, a.wsrt, A2);
  gbar(a.lines, a.gbl, ++nb, gdim);
  hopb_phase<false>(A2, 32, Y2 + 1 * 32, 192, a.ptrA, a.srcs, a.wsrt, B2);
  gbar(a.lines, a.gbl, ++nb, gdim);
  hopb_phase<true>(B2, 32, Y2 + 0 * 32, 192, a.ptrA, a.srcs, a.wsrt, D2);
  gbar(a.lines, a.gbl, ++nb, gdim);
  // h2 = D (bf16)

  // ===== layer 3: GEMM (X = D bf16 -> fp32 ybuf = A [N][64]) then hop10 chain =====
  float* ybuf = (float*)a.A;
  float* z0 = (float*)a.B;
  float* z1 = (float*)(a.B + (size_t)N_NODES * 16 * 4);
  for (int t = blockIdx.x; t < TG1; t += gdim)
    gemm_tile<HDIM, 1, true, false>(a.D, a.W3, a.b3, true, ybuf, 64, t, xt, bt);
  gbar(a.lines, a.gbl, ++nb, gdim);
  hop10_phase(ybuf, 64, 50, ybuf, 40, a.ptrA, a.srcs, a.wsrt, z0); gbar(a.lines, a.gbl, ++nb, gdim);
  hop10_phase(z0, 10, 0, ybuf, 30, a.ptrA, a.srcs, a.wsrt, z1); gbar(a.lines, a.gbl, ++nb, gdim);
  hop10_phase(z1, 10, 0, ybuf, 20, a.ptrA, a.srcs, a.wsrt, z0); gbar(a.lines, a.gbl, ++nb, gdim);
  hop10_phase(z0, 10, 0, ybuf, 10, a.ptrA, a.srcs, a.wsrt, z1); gbar(a.lines, a.gbl, ++nb, gdim);
  hop10_phase(z1, 10, 0, ybuf, 0, a.ptrA, a.srcs, a.wsrt, a.out);
}

// ---------------- host ----------------

extern "C" void kernel_launch(void* const* d_in, const int* in_sizes, int n_in,
                              void* d_out, int out_size, void* d_ws, size_t ws_size,
                              hipStream_t stream) {
  Args a;
  a.x  = (const float*)d_in[0];
  a.ei = (const int*)d_in[1];
  a.ew = (const float*)d_in[2];
  a.W1 = (const float*)d_in[3];
  a.b1 = (const float*)d_in[4];
  a.W2 = (const float*)d_in[5];
  a.b2 = (const float*)d_in[6];
  a.W3 = (const float*)d_in[7];
  a.b3 = (const float*)d_in[8];
  a.out = (float*)d_out;

  const int N = N_NODES, E = N_EDGES;
  char* base = (char*)d_ws;
  size_t off = 0;
  auto alloc = [&](size_t bytes) -> char* {
    char* p = base + off;
    off += (bytes + 255) & ~(size_t)255;
    return p;
  };
  a.Yall = (ushortT*)alloc((size_t)N * 768 * 2);   // 76.8 MB (bf16)
  a.A = alloc((size_t)N * 256);
  a.B = alloc((size_t)N * 256);
  a.C = (ushortT*)alloc((size_t)N * 128 * 2);
  a.D = (ushortT*)alloc((size_t)N * 128 * 2);
  a.ptrA = (int*)alloc((size_t)(N + 1) * 4);
  a.pos  = (int*)alloc((size_t)N * 4);
  a.srcs = (int*)alloc((size_t)E * 4);
  a.wsrt = (float*)alloc((size_t)E * 4);
  a.lines = (int*)alloc(NLINES * 32 * 4);          // padded arrival lines
  a.gbl   = (int*)alloc(256);

  // prep transients overlay A (A first written by the first layer-1 hop, after P5).
  char* t = a.A;
  a.row32 = (int*)t;            t += (size_t)E * 4;
  a.col32 = (int*)t;            t += (size_t)E * 4;
  a.deg   = (float*)t;          t += (size_t)N * 4;
  a.dis   = (float*)t;          t += (size_t)N * 4;
  a.cnt   = (int*)t;            t += (size_t)N * 4;
  a.part  = (int*)t;            t += 2048 * 4;

  hipMemsetAsync(a.lines, 0, NLINES * 32 * 4, stream);
  hipMemsetAsync(a.gbl, 0, 256, stream);
  hipMemsetAsync(a.deg, 0, (size_t)N * 4, stream);
  hipMemsetAsync(a.cnt, 0, (size_t)N * 4, stream);

  int occ = 0;
  hipOccupancyMaxActiveBlocksPerMultiprocessor(&occ, (const void*)mega_kernel, 256, 0);
  int grid = occ * 256;
  if (grid > 1024) grid = 1024;
  if (grid < 64) grid = 64;
  grid &= ~(NLINES - 1);          // gbar requires gdim % NLINES == 0

  void* args[] = { &a };
  hipLaunchCooperativeKernel((const void*)mega_kernel, dim3(grid), dim3(256), args, 0, stream);

  (void)in_sizes; (void)n_in; (void)out_size; (void)ws_size;
}

// Round 16
// 4200.532 us; speedup vs baseline: 3.7854x; 1.0057x over previous
//
#include <hip/hip_runtime.h>
#include <cstdint>
#include <cstddef>

#define N_NODES 50000
#define N_EDGES 800000
#define F_IN_D 100
#define HDIM 128
#define CDIM 10
#define NCH ((N_NODES + 255) / 256)   // 196 scan chunks
#define NLINES 64                     // barrier arrival lines (padded cache lines)

typedef unsigned short ushortT;

__device__ __forceinline__ float bf2f(unsigned int b16) {
  return __uint_as_float(b16 << 16);
}
__device__ __forceinline__ unsigned int f2bf(float f) {   // RNE bf16
  unsigned int u = __float_as_uint(f);
  unsigned int r = u + 0x7FFFu + ((u >> 16) & 1u);
  return r >> 16;
}

struct Args {
  const float* x; const int* ei; const float* ew;
  const float* W1; const float* b1;
  const float* W2; const float* b2;
  const float* W3; const float* b3;
  float* out;
  ushortT* Yall;                       // bf16 [N][768]
  char* A; char* B;                    // bf16 [N][128] ping-pong (fp32 [N][64] ybuf / z in layer 3)
  ushortT* C; ushortT* D;              // h1, h2 (bf16 [N][128])
  int* ptrA; int* pos; int* srcs; float* wsrt;
  int* row32; int* col32; float* deg; float* dis; int* cnt; int* part;
  int* lines;                          // NLINES padded arrival counters (host-zeroed)
  int* gbl;                            // global phase counter (host-zeroed)
};

// ---- grid barrier v4: two-level arrival (NLINES padded lines), ACQUIRE poll ----
// gdim MUST be a multiple of NLINES. Last arriver per line bumps the global counter.
__device__ __forceinline__ void gbar(int* lines, int* gbl, int round, int gdim) {
  __syncthreads();
  if (threadIdx.x == 0) {
    __threadfence();                                   // release
    const int perLine = gdim / NLINES;
    int old = atomicAdd(&lines[(blockIdx.x & (NLINES - 1)) * 32], 1);
    if (old == round * perLine - 1) atomicAdd(gbl, 1);
    while (__hip_atomic_load(gbl, __ATOMIC_ACQUIRE, __HIP_MEMORY_SCOPE_AGENT) < round * NLINES)
      __builtin_amdgcn_s_sleep(8);
    __threadfence();                                   // acquire
  }
  __syncthreads();
}

// ---- GEMM tile: out[n0:+64, c0:+64] = X @ B (+bias if addb) ----
template <int K_DIM, int BMODE, bool XBF, bool OUTBF>
__device__ __forceinline__ void gemm_tile(const void* __restrict__ Xv, const float* __restrict__ W,
                                          const float* __restrict__ bias, bool addb,
                                          void* __restrict__ outv, int ostride, int tile,
                                          float (&xt)[32][68], float (&bt)[32][64]) {
  const int tid = threadIdx.x;
  const int tx = tid & 15;
  const int ty = tid >> 4;
  int n0, c0;
  if (BMODE == 0) { n0 = (tile >> 1) * 64; c0 = (tile & 1) * 64; }
  else            { n0 = tile * 64;        c0 = 0; }
  float acc[4][4];
#pragma unroll
  for (int i = 0; i < 4; ++i)
#pragma unroll
    for (int j = 0; j < 4; ++j) acc[i][j] = 0.f;

  for (int k0 = 0; k0 < K_DIM; k0 += 32) {
#pragma unroll
    for (int i = 0; i < 8; ++i) {
      int idx = tid + i * 256;
      int nl = idx >> 5, kl = idx & 31;
      int nn = n0 + nl, kg = k0 + kl;
      float v = 0.f;
      if (nn < N_NODES && kg < K_DIM) {
        if (XBF) v = bf2f(((const ushortT*)Xv)[(size_t)nn * K_DIM + kg]);
        else     v = ((const float*)Xv)[(size_t)nn * K_DIM + kg];
      }
      xt[kl][nl] = v;
    }
#pragma unroll
    for (int i = 0; i < 8; ++i) {
      int idx = tid + i * 256;
      int kl = idx >> 6, cl = idx & 63;
      int kg = k0 + kl;
      float v = 0.f;
      if (BMODE == 0) {
        if (kg < K_DIM) v = W[(size_t)kg * 128 + c0 + cl];
      } else {
        if (kg < K_DIM && cl < 6 * CDIM)
          v = W[(size_t)(cl / CDIM) * (K_DIM * CDIM) + (size_t)kg * CDIM + (cl % CDIM)];
      }
      bt[kl][cl] = v;
    }
    __syncthreads();
#pragma unroll
    for (int kk = 0; kk < 32; ++kk) {
      float4 xv = *(const float4*)&xt[kk][tx * 4];
      float4 bv = *(const float4*)&bt[kk][ty * 4];
      acc[0][0] += xv.x * bv.x; acc[0][1] += xv.x * bv.y; acc[0][2] += xv.x * bv.z; acc[0][3] += xv.x * bv.w;
      acc[1][0] += xv.y * bv.x; acc[1][1] += xv.y * bv.y; acc[1][2] += xv.y * bv.z; acc[1][3] += xv.y * bv.w;
      acc[2][0] += xv.z * bv.x; acc[2][1] += xv.z * bv.y; acc[2][2] += xv.z * bv.z; acc[2][3] += xv.z * bv.w;
      acc[3][0] += xv.w * bv.x; acc[3][1] += xv.w * bv.y; acc[3][2] += xv.w * bv.z; acc[3][3] += xv.w * bv.w;
    }
    __syncthreads();
  }
#pragma unroll
  for (int i = 0; i < 4; ++i) {
    int nn = n0 + tx * 4 + i;
    if (nn >= N_NODES) continue;
#pragma unroll
    for (int j = 0; j < 4; ++j) {
      int c = c0 + ty * 4 + j;
      if (addb) {
        if (BMODE == 0) acc[i][j] += bias[c];
        else if (c < CDIM) acc[i][j] += bias[c];
      }
    }
    if (OUTBF) {
      uint2 o;
      o.x = f2bf(acc[i][0]) | (f2bf(acc[i][1]) << 16);
      o.y = f2bf(acc[i][2]) | (f2bf(acc[i][3]) << 16);
      *(uint2*)&((ushortT*)outv)[(size_t)nn * ostride + c0 + ty * 4] = o;
    } else {
#pragma unroll
      for (int j = 0; j < 4; ++j)
        ((float*)outv)[(size_t)nn * ostride + c0 + ty * 4 + j] = acc[i][j];
    }
  }
}

// ---- bf16 hop d=128, half-wave per node, 8-deep gather pipeline ----
template <bool ELU>
__device__ __forceinline__ void hopb_phase(const uint2* __restrict__ P2, int pstr,
                                           const uint2* __restrict__ Y2, int ystr,
                                           const int* __restrict__ ptr, const int* __restrict__ srcs,
                                           const float* __restrict__ w, uint2* __restrict__ Q2) {
  const int hw = threadIdx.x >> 5;             // 8 half-waves per 256-thread block
  const int f4 = threadIdx.x & 31;
  for (int node = blockIdx.x * 8 + hw; node < N_NODES; node += gridDim.x * 8) {
    const int b = ptr[node], e = ptr[node + 1];
    uint2 yv = Y2[(size_t)node * ystr + f4];
    float a0 = bf2f(yv.x & 0xFFFFu), a1 = bf2f(yv.x >> 16);
    float a2 = bf2f(yv.y & 0xFFFFu), a3 = bf2f(yv.y >> 16);
    int j = b;
    for (; j + 7 < e; j += 8) {
      int s0 = srcs[j], s1 = srcs[j + 1], s2 = srcs[j + 2], s3 = srcs[j + 3];
      int s4 = srcs[j + 4], s5 = srcs[j + 5], s6 = srcs[j + 6], s7 = srcs[j + 7];
      float w0 = w[j], w1 = w[j + 1], w2 = w[j + 2], w3 = w[j + 3];
      float w4 = w[j + 4], w5 = w[j + 5], w6 = w[j + 6], w7 = w[j + 7];
      uint2 v0 = P2[(size_t)s0 * pstr + f4];
      uint2 v1 = P2[(size_t)s1 * pstr + f4];
      uint2 v2 = P2[(size_t)s2 * pstr + f4];
      uint2 v3 = P2[(size_t)s3 * pstr + f4];
      uint2 v4 = P2[(size_t)s4 * pstr + f4];
      uint2 v5 = P2[(size_t)s5 * pstr + f4];
      uint2 v6 = P2[(size_t)s6 * pstr + f4];
      uint2 v7 = P2[(size_t)s7 * pstr + f4];
      a0 += w0 * bf2f(v0.x & 0xFFFFu) + w1 * bf2f(v1.x & 0xFFFFu) + w2 * bf2f(v2.x & 0xFFFFu) + w3 * bf2f(v3.x & 0xFFFFu)
          + w4 * bf2f(v4.x & 0xFFFFu) + w5 * bf2f(v5.x & 0xFFFFu) + w6 * bf2f(v6.x & 0xFFFFu) + w7 * bf2f(v7.x & 0xFFFFu);
      a1 += w0 * bf2f(v0.x >> 16) + w1 * bf2f(v1.x >> 16) + w2 * bf2f(v2.x >> 16) + w3 * bf2f(v3.x >> 16)
          + w4 * bf2f(v4.x >> 16) + w5 * bf2f(v5.x >> 16) + w6 * bf2f(v6.x >> 16) + w7 * bf2f(v7.x >> 16);
      a2 += w0 * bf2f(v0.y & 0xFFFFu) + w1 * bf2f(v1.y & 0xFFFFu) + w2 * bf2f(v2.y & 0xFFFFu) + w3 * bf2f(v3.y & 0xFFFFu)
          + w4 * bf2f(v4.y & 0xFFFFu) + w5 * bf2f(v5.y & 0xFFFFu) + w6 * bf2f(v6.y & 0xFFFFu) + w7 * bf2f(v7.y & 0xFFFFu);
      a3 += w0 * bf2f(v0.y >> 16) + w1 * bf2f(v1.y >> 16) + w2 * bf2f(v2.y >> 16) + w3 * bf2f(v3.y >> 16)
          + w4 * bf2f(v4.y >> 16) + w5 * bf2f(v5.y >> 16) + w6 * bf2f(v6.y >> 16) + w7 * bf2f(v7.y >> 16);
    }
    for (; j + 1 < e; j += 2) {
      int s0 = srcs[j], s1 = srcs[j + 1];
      float w0 = w[j], w1 = w[j + 1];
      uint2 v0 = P2[(size_t)s0 * pstr + f4];
      uint2 v1 = P2[(size_t)s1 * pstr + f4];
      a0 += w0 * bf2f(v0.x & 0xFFFFu) + w1 * bf2f(v1.x & 0xFFFFu);
      a1 += w0 * bf2f(v0.x >> 16)     + w1 * bf2f(v1.x >> 16);
      a2 += w0 * bf2f(v0.y & 0xFFFFu) + w1 * bf2f(v1.y & 0xFFFFu);
      a3 += w0 * bf2f(v0.y >> 16)     + w1 * bf2f(v1.y >> 16);
    }
    if (j < e) {
      float w0 = w[j];
      uint2 v0 = P2[(size_t)srcs[j] * pstr + f4];
      a0 += w0 * bf2f(v0.x & 0xFFFFu);
      a1 += w0 * bf2f(v0.x >> 16);
      a2 += w0 * bf2f(v0.y & 0xFFFFu);
      a3 += w0 * bf2f(v0.y >> 16);
    }
    if (ELU) {
      a0 = a0 > 0.f ? a0 : expm1f(a0);
      a1 = a1 > 0.f ? a1 : expm1f(a1);
      a2 = a2 > 0.f ? a2 : expm1f(a2);
      a3 = a3 > 0.f ? a3 : expm1f(a3);
    }
    uint2 o;
    o.x = f2bf(a0) | (f2bf(a1) << 16);
    o.y = f2bf(a2) | (f2bf(a3) << 16);
    Q2[(size_t)node * 32 + f4] = o;
  }
}

// ---- hop d=10 (fp32, unchanged) ----
__device__ __forceinline__ void hop10_phase(const float* __restrict__ z, int zStride, int zOff,
                                            const float* __restrict__ ybuf, int yOff,
                                            const int* __restrict__ ptr, const int* __restrict__ srcs,
                                            const float* __restrict__ wsrt, float* __restrict__ outp) {
  const int lane = threadIdx.x & 63;
  const int wid = threadIdx.x >> 6;
  const int sub = lane >> 4;
  const int f = lane & 15;
  for (int node = blockIdx.x * 4 + wid; node < N_NODES; node += gridDim.x * 4) {
    const int b = ptr[node], e = ptr[node + 1];
    const int len = e - b;
    const int js = b + (len * sub) / 4;
    const int je = b + (len * (sub + 1)) / 4;
    float acc = 0.f;
    if (f < CDIM) {
      if (sub == 0) acc = ybuf[(size_t)node * 64 + yOff + f];
      int j = js;
      for (; j + 1 < je; j += 2) {
        int s0 = srcs[j], s1 = srcs[j + 1];
        float w0 = wsrt[j], w1 = wsrt[j + 1];
        acc += w0 * z[(size_t)s0 * zStride + zOff + f] + w1 * z[(size_t)s1 * zStride + zOff + f];
      }
      if (j < je) acc += wsrt[j] * z[(size_t)srcs[j] * zStride + zOff + f];
    }
    acc += __shfl_xor(acc, 16);
    acc += __shfl_xor(acc, 32);
    if (sub == 0 && f < CDIM) outp[(size_t)node * CDIM + f] = acc;
  }
}

// ================= persistent kernel, 21 barriers =================
__global__ __launch_bounds__(256, 4) void mega_kernel(Args a) {
  __shared__ float xt[32][68];
  __shared__ float bt[32][64];
  __shared__ int sdi[256];
  const int tid = threadIdx.x;
  const int gtid = blockIdx.x * blockDim.x + tid;
  const int gstride = gridDim.x * blockDim.x;
  const int gdim = gridDim.x;
  const int TG0 = ((N_NODES + 63) / 64) * 2;   // 1564
  const int TG1 = (N_NODES + 63) / 64;         // 782
  int nb = 0;

  // P1: convert edges + degree atomics, then layer-1 GEMM (independent of prep)
  {
    bool is64 = true;
    for (int i = 0; i < 32; ++i) if (a.ei[2 * i + 1] != 0) is64 = false;
    for (int e = gtid; e < N_EDGES; e += gstride) {
      int r, c;
      if (is64) { r = a.ei[2 * e]; c = a.ei[2 * (N_EDGES + e)]; }
      else      { r = a.ei[e];     c = a.ei[N_EDGES + e]; }
      a.row32[e] = r; a.col32[e] = c;
      atomicAdd(&a.deg[c], a.ew[e]);
      atomicAdd(&a.cnt[c], 1);
    }
  }
  for (int job = blockIdx.x; job < 6 * TG0; job += gdim) {
    int k = job / TG0, t = job % TG0;
    gemm_tile<F_IN_D, 0, false, true>(a.x, a.W1 + (size_t)k * F_IN_D * 128, a.b1, k == 0,
                                      a.Yall + k * 128, 768, t, xt, bt);
  }
  gbar(a.lines, a.gbl, ++nb, gdim);

  // P2: dis + per-chunk count sums
  for (int i = gtid; i < N_NODES; i += gstride) {
    float d = a.deg[i];
    a.dis[i] = d > 0.f ? rsqrtf(fmaxf(d, 1e-12f)) : 0.f;
  }
  for (int c = blockIdx.x; c < NCH; c += gdim) {
    int i = c * 256 + tid;
    sdi[tid] = (i < N_NODES) ? a.cnt[i] : 0;
    __syncthreads();
    for (int s = 128; s > 0; s >>= 1) { if (tid < s) sdi[tid] += sdi[tid + s]; __syncthreads(); }
    if (tid == 0) a.part[c] = sdi[0];
    __syncthreads();
  }
  gbar(a.lines, a.gbl, ++nb, gdim);

  // P3: block 0 scans the 196 partials
  if (blockIdx.x == 0) {
    int v = (tid < NCH) ? a.part[tid] : 0;
    sdi[tid] = v;
    __syncthreads();
    for (int o = 1; o < 256; o <<= 1) {
      int t2 = (tid >= o) ? sdi[tid - o] : 0;
      __syncthreads();
      sdi[tid] += t2;
      __syncthreads();
    }
    if (tid < NCH) a.part[tid] = sdi[tid] - v;
    if (tid == 255) a.ptrA[N_NODES] = sdi[255];
  }
  gbar(a.lines, a.gbl, ++nb, gdim);

  // P4: per-chunk exclusive scan -> ptrA, pos
  for (int c = blockIdx.x; c < NCH; c += gdim) {
    int i = c * 256 + tid;
    int v = (i < N_NODES) ? a.cnt[i] : 0;
    sdi[tid] = v;
    __syncthreads();
    for (int o = 1; o < 256; o <<= 1) {
      int t2 = (tid >= o) ? sdi[tid - o] : 0;
      __syncthreads();
      sdi[tid] += t2;
      __syncthreads();
    }
    if (i < N_NODES) { int p = a.part[c] + sdi[tid] - v; a.ptrA[i] = p; a.pos[i] = p; }
    __syncthreads();
  }
  gbar(a.lines, a.gbl, ++nb, gdim);

  // P5: place into CSC + fused norm
  for (int e = gtid; e < N_EDGES; e += gstride) {
    int r = a.row32[e], c = a.col32[e];
    int slot = atomicAdd(&a.pos[c], 1);
    a.srcs[slot] = r;
    a.wsrt[slot] = a.dis[r] * a.ew[e] * a.dis[c];
  }
  gbar(a.lines, a.gbl, ++nb, gdim);

  const uint2* Y2 = (const uint2*)a.Yall;      // row stride 192 uint2; y_k at offset k*32
  uint2* A2 = (uint2*)a.A; uint2* B2 = (uint2*)a.B;
  uint2* C2 = (uint2*)a.C; uint2* D2 = (uint2*)a.D;

  // ===== layer 1 hops =====
  hopb_phase<false>(Y2 + 5 * 32, 192, Y2 + 4 * 32, 192, a.ptrA, a.srcs, a.wsrt, A2);
  gbar(a.lines, a.gbl, ++nb, gdim);
  hopb_phase<false>(A2, 32, Y2 + 3 * 32, 192, a.ptrA, a.srcs, a.wsrt, B2);
  gbar(a.lines, a.gbl, ++nb, gdim);
  hopb_phase<false>(B2, 32, Y2 + 2 * 32, 192, a.ptrA, a.srcs, a.wsrt, A2);
  gbar(a.lines, a.gbl, ++nb, gdim);
  hopb_phase<false>(A2, 32, Y2 + 1 * 32, 192, a.ptrA, a.srcs, a.wsrt, B2);
  gbar(a.lines, a.gbl, ++nb, gdim);
  hopb_phase<true>(B2, 32, Y2 + 0 * 32, 192, a.ptrA, a.srcs, a.wsrt, C2);
  gbar(a.lines, a.gbl, ++nb, gdim);
  // h1 = C (bf16)

  // ===== layer 2: GEMM (X = C bf16) then hops =====
  for (int job = blockIdx.x; job < 6 * TG0; job += gdim) {
    int k = job / TG0, t = job % TG0;
    gemm_tile<HDIM, 0, true, true>(a.C, a.W2 + (size_t)k * HDIM * 128, a.b2, k == 0,
                                   a.Yall + k * 128, 768, t, xt, bt);
  }
  gbar(a.lines, a.gbl, ++nb, gdim);
  hopb_phase<false>(Y2 + 5 * 32, 192, Y2 + 4 * 32, 192, a.ptrA, a.srcs, a.wsrt, A2);
  gbar(a.lines, a.gbl, ++nb, gdim);
  hopb_phase<false>(A2, 32, Y2 + 3 * 32, 192, a.ptrA, a.srcs, a.wsrt, B2);
  gbar(a.lines, a.gbl, ++nb, gdim);
  hopb_phase<false>(B2, 32, Y2 + 2 * 32, 192, a.ptrA, a.srcs, a.wsrt, A2);
  gbar(a.lines, a.gbl, ++nb, gdim);
  hopb_phase<false>(A2, 32, Y2 + 1 * 32, 192, a.ptrA, a.srcs, a.wsrt, B2);
  gbar(a.lines, a.gbl, ++nb, gdim);
  hopb_phase<true>(B2, 32, Y2 + 0 * 32, 192, a.ptrA, a.srcs, a.wsrt, D2);
  gbar(a.lines, a.gbl, ++nb, gdim);
  // h2 = D (bf16)

  // ===== layer 3: GEMM (X = D bf16 -> fp32 ybuf = A [N][64]) then hop10 chain =====
  float* ybuf = (float*)a.A;
  float* z0 = (float*)a.B;
  float* z1 = (float*)(a.B + (size_t)N_NODES * 16 * 4);
  for (int t = blockIdx.x; t < TG1; t += gdim)
    gemm_tile<HDIM, 1, true, false>(a.D, a.W3, a.b3, true, ybuf, 64, t, xt, bt);
  gbar(a.lines, a.gbl, ++nb, gdim);
  hop10_phase(ybuf, 64, 50, ybuf, 40, a.ptrA, a.srcs, a.wsrt, z0); gbar(a.lines, a.gbl, ++nb, gdim);
  hop10_phase(z0, 10, 0, ybuf, 30, a.ptrA, a.srcs, a.wsrt, z1); gbar(a.lines, a.gbl, ++nb, gdim);
  hop10_phase(z1, 10, 0, ybuf, 20, a.ptrA, a.srcs, a.wsrt, z0); gbar(a.lines, a.gbl, ++nb, gdim);
  hop10_phase(z0, 10, 0, ybuf, 10, a.ptrA, a.srcs, a.wsrt, z1); gbar(a.lines, a.gbl, ++nb, gdim);
  hop10_phase(z1, 10, 0, ybuf, 0, a.ptrA, a.srcs, a.wsrt, a.out);
}

// ---------------- host ----------------

extern "C" void kernel_launch(void* const* d_in, const int* in_sizes, int n_in,
                              void* d_out, int out_size, void* d_ws, size_t ws_size,
                              hipStream_t stream) {
  Args a;
  a.x  = (const float*)d_in[0];
  a.ei = (const int*)d_in[1];
  a.ew = (const float*)d_in[2];
  a.W1 = (const float*)d_in[3];
  a.b1 = (const float*)d_in[4];
  a.W2 = (const float*)d_in[5];
  a.b2 = (const float*)d_in[6];
  a.W3 = (const float*)d_in[7];
  a.b3 = (const float*)d_in[8];
  a.out = (float*)d_out;

  const int N = N_NODES, E = N_EDGES;
  char* base = (char*)d_ws;
  size_t off = 0;
  auto alloc = [&](size_t bytes) -> char* {
    char* p = base + off;
    off += (bytes + 255) & ~(size_t)255;
    return p;
  };
  a.Yall = (ushortT*)alloc((size_t)N * 768 * 2);   // 76.8 MB (bf16)
  a.A = alloc((size_t)N * 256);
  a.B = alloc((size_t)N * 256);
  a.C = (ushortT*)alloc((size_t)N * 128 * 2);
  a.D = (ushortT*)alloc((size_t)N * 128 * 2);
  a.ptrA = (int*)alloc((size_t)(N + 1) * 4);
  a.pos  = (int*)alloc((size_t)N * 4);
  a.srcs = (int*)alloc((size_t)E * 4);
  a.wsrt = (float*)alloc((size_t)E * 4);
  a.lines = (int*)alloc(NLINES * 32 * 4);          // padded arrival lines
  a.gbl   = (int*)alloc(256);

  // prep transients overlay A (A first written by the first layer-1 hop, after P5).
  char* t = a.A;
  a.row32 = (int*)t;            t += (size_t)E * 4;
  a.col32 = (int*)t;            t += (size_t)E * 4;
  a.deg   = (float*)t;          t += (size_t)N * 4;
  a.dis   = (float*)t;          t += (size_t)N * 4;
  a.cnt   = (int*)t;            t += (size_t)N * 4;
  a.part  = (int*)t;            t += 2048 * 4;

  hipMemsetAsync(a.lines, 0, NLINES * 32 * 4, stream);
  hipMemsetAsync(a.gbl, 0, 256, stream);
  hipMemsetAsync(a.deg, 0, (size_t)N * 4, stream);
  hipMemsetAsync(a.cnt, 0, (size_t)N * 4, stream);

  int occ = 0;
  hipOccupancyMaxActiveBlocksPerMultiprocessor(&occ, (const void*)mega_kernel, 256, 0);
  if (occ < 1) occ = 1;
  int grid = occ * 256;           // 256 CUs on MI355X
  if (grid > 2048) grid = 2048;   // full-residency cap (8 blocks/CU)
  if (grid < 64) grid = 64;
  grid &= ~(NLINES - 1);          // gbar requires gdim % NLINES == 0

  void* args[] = { &a };
  hipLaunchCooperativeKernel((const void*)mega_kernel, dim3(grid), dim3(256), args, 0, stream);

  (void)in_sizes; (void)n_in; (void)out_size; (void)ws_size;
}